// Round 7
// baseline (296.697 us; speedup 1.0000x reference)
//
#include <hip/hip_runtime.h>
#include <stdint.h>

#define NN 4096
#define NGG 4096
#define NUU 8192

// monotone float->uint mapping (order-preserving incl. negatives)
__device__ __forceinline__ unsigned fkey32(float f) {
  unsigned u = __float_as_uint(f);
  return u ^ (((int)u >> 31) | 0x80000000u);
}
__device__ __forceinline__ float unfkey32(unsigned k) {
  unsigned m = (k & 0x80000000u) ? 0x80000000u : 0xFFFFFFFFu;
  return __uint_as_float(k ^ m);
}

// ---------------- block-wide sum (blockDim.x == 512) -------------------
__device__ __forceinline__ float block_sum_512(float v, float* sbuf) {
#pragma unroll
  for (int o = 32; o > 0; o >>= 1) v += __shfl_down(v, o, 64);
  int lane = threadIdx.x & 63;
  int w = threadIdx.x >> 6;
  if (lane == 0) sbuf[w] = v;
  __syncthreads();
  float r = 0.f;
  if (threadIdx.x == 0) {
#pragma unroll
    for (int i = 0; i < 8; ++i) r += sbuf[i];
  }
  __syncthreads();
  return r;
}

// ---------------- fused scan: argmin + chamfer rows + chamfer cols -----
// R2-proven layout (Q=4, 1280 blocks). Block 0 additionally zeroes acc
// (replaces a host-side memset dispatch; acc is only consumed by later
// kernels in the same stream).
// blocks [0,512): cham_row  (65536 queries, gt candidates, 8 segs x 512)
// blocks [512,1024): cham_col (32768 queries, up/off candidates, 16 segs x 512)
// blocks [1024,1280): argmin (16384 queries, gt candidates, 16 segs x 256)
__global__ __launch_bounds__(256) void k_scan(const float* __restrict__ pts,
                                              const float* __restrict__ gt,
                                              const float* __restrict__ up,
                                              const float* __restrict__ off,
                                              unsigned long long* __restrict__ keys,
                                              unsigned* __restrict__ rowmin,
                                              unsigned* __restrict__ colmin,
                                              float* __restrict__ acc) {
  __shared__ float4 sc[512];   // 8 KB
  int blk = blockIdx.x;
  int tid = threadIdx.x;
  if (blk == 0 && tid < 16) acc[tid] = 0.f;

  if (blk < 512) {
    // ------- cham_row: up/off points vs gt candidates -------
    int qb = blk >> 3;           // [0,64)
    int seg = blk & 7;           // [0,8)
    int wb = qb >> 3;            // [0,8)
    int which = wb >> 2;         // 0=off, 1=up
    int b = wb & 3;
    int r0 = (qb & 7) * 1024 + tid * 4;   // [0,8192)
    {
      const float* gtb = gt + (size_t)b * NGG * 6 + (size_t)seg * 512 * 6;
      int i0 = tid * 2;
      const float4* g4 = (const float4*)(gtb + (size_t)i0 * 6);
      float4 u0 = g4[0], u1 = g4[1], u2 = g4[2];
      sc[i0] = make_float4(u0.x, u0.y, u0.z,
                           fmaf(u0.x, u0.x, fmaf(u0.y, u0.y, u0.z * u0.z)));
      sc[i0 + 1] = make_float4(u1.z, u1.w, u2.x,
                               fmaf(u1.z, u1.z, fmaf(u1.w, u1.w, u2.x * u2.x)));
    }
    const float* src = which ? up : off;
    const float4* s4 = (const float4*)src;
    size_t fb = ((size_t)(b * NUU + r0) * 3) >> 2;
    float4 A = s4[fb], B = s4[fb + 1], C = s4[fb + 2];
    float q0x = A.x, q0y = A.y, q0z = A.z;
    float q1x = A.w, q1y = B.x, q1z = B.y;
    float q2x = B.z, q2y = B.w, q2z = C.x;
    float q3x = C.y, q3y = C.z, q3z = C.w;
    float qq0 = fmaf(q0x, q0x, fmaf(q0y, q0y, q0z * q0z));
    float qq1 = fmaf(q1x, q1x, fmaf(q1y, q1y, q1z * q1z));
    float qq2 = fmaf(q2x, q2x, fmaf(q2y, q2y, q2z * q2z));
    float qq3 = fmaf(q3x, q3x, fmaf(q3y, q3y, q3z * q3z));
    float a0x = -2.f * q0x, a0y = -2.f * q0y, a0z = -2.f * q0z;
    float a1x = -2.f * q1x, a1y = -2.f * q1y, a1z = -2.f * q1z;
    float a2x = -2.f * q2x, a2y = -2.f * q2y, a2z = -2.f * q2z;
    float a3x = -2.f * q3x, a3y = -2.f * q3y, a3z = -2.f * q3z;
    __syncthreads();
    float b0 = 3.4e38f, b1 = 3.4e38f, b2 = 3.4e38f, b3 = 3.4e38f;
#pragma unroll 4
    for (int j = 0; j < 512; ++j) {
      float4 c = sc[j];
      float t;
      t = fmaf(c.x, a0x, c.w); t = fmaf(c.y, a0y, t); t = fmaf(c.z, a0z, t); b0 = fminf(b0, t);
      t = fmaf(c.x, a1x, c.w); t = fmaf(c.y, a1y, t); t = fmaf(c.z, a1z, t); b1 = fminf(b1, t);
      t = fmaf(c.x, a2x, c.w); t = fmaf(c.y, a2y, t); t = fmaf(c.z, a2z, t); b2 = fminf(b2, t);
      t = fmaf(c.x, a3x, c.w); t = fmaf(c.y, a3y, t); t = fmaf(c.z, a3z, t); b3 = fminf(b3, t);
    }
    int gr = which * 32768 + b * NUU + r0;
    atomicMin(&rowmin[gr + 0], fkey32(b0 + qq0));
    atomicMin(&rowmin[gr + 1], fkey32(b1 + qq1));
    atomicMin(&rowmin[gr + 2], fkey32(b2 + qq2));
    atomicMin(&rowmin[gr + 3], fkey32(b3 + qq3));

  } else if (blk < 1024) {
    // ------- cham_col: gt points vs up/off candidates -------
    int blk2 = blk - 512;
    int qb = blk2 >> 4;          // [0,32)
    int seg = blk2 & 15;         // [0,16)
    int which = qb >> 4;         // 0=off, 1=up
    int b = (qb >> 2) & 3;
    int m0 = (qb & 3) * 1024 + tid * 4;   // [0,4096)
    const float* src = which ? up : off;
    if (tid < 128) {
      const float* sb = src + (size_t)b * NUU * 3 + (size_t)seg * 512 * 3;
      int i0 = tid * 4;
      const float4* s4 = (const float4*)(sb + (size_t)i0 * 3);
      float4 u0 = s4[0], u1 = s4[1], u2 = s4[2];
      sc[i0] = make_float4(u0.x, u0.y, u0.z,
                           fmaf(u0.x, u0.x, fmaf(u0.y, u0.y, u0.z * u0.z)));
      sc[i0 + 1] = make_float4(u0.w, u1.x, u1.y,
                               fmaf(u0.w, u0.w, fmaf(u1.x, u1.x, u1.y * u1.y)));
      sc[i0 + 2] = make_float4(u1.z, u1.w, u2.x,
                               fmaf(u1.z, u1.z, fmaf(u1.w, u1.w, u2.x * u2.x)));
      sc[i0 + 3] = make_float4(u2.y, u2.z, u2.w,
                               fmaf(u2.y, u2.y, fmaf(u2.z, u2.z, u2.w * u2.w)));
    }
    const float* g = gt + (size_t)b * NGG * 6 + (size_t)m0 * 6;
    float q0x = g[0],  q0y = g[1],  q0z = g[2];
    float q1x = g[6],  q1y = g[7],  q1z = g[8];
    float q2x = g[12], q2y = g[13], q2z = g[14];
    float q3x = g[18], q3y = g[19], q3z = g[20];
    float qq0 = fmaf(q0x, q0x, fmaf(q0y, q0y, q0z * q0z));
    float qq1 = fmaf(q1x, q1x, fmaf(q1y, q1y, q1z * q1z));
    float qq2 = fmaf(q2x, q2x, fmaf(q2y, q2y, q2z * q2z));
    float qq3 = fmaf(q3x, q3x, fmaf(q3y, q3y, q3z * q3z));
    float a0x = -2.f * q0x, a0y = -2.f * q0y, a0z = -2.f * q0z;
    float a1x = -2.f * q1x, a1y = -2.f * q1y, a1z = -2.f * q1z;
    float a2x = -2.f * q2x, a2y = -2.f * q2y, a2z = -2.f * q2z;
    float a3x = -2.f * q3x, a3y = -2.f * q3y, a3z = -2.f * q3z;
    __syncthreads();
    float b0 = 3.4e38f, b1 = 3.4e38f, b2 = 3.4e38f, b3 = 3.4e38f;
#pragma unroll 4
    for (int j = 0; j < 512; ++j) {
      float4 c = sc[j];
      float t;
      t = fmaf(c.x, a0x, c.w); t = fmaf(c.y, a0y, t); t = fmaf(c.z, a0z, t); b0 = fminf(b0, t);
      t = fmaf(c.x, a1x, c.w); t = fmaf(c.y, a1y, t); t = fmaf(c.z, a1z, t); b1 = fminf(b1, t);
      t = fmaf(c.x, a2x, c.w); t = fmaf(c.y, a2y, t); t = fmaf(c.z, a2z, t); b2 = fminf(b2, t);
      t = fmaf(c.x, a3x, c.w); t = fmaf(c.y, a3y, t); t = fmaf(c.z, a3z, t); b3 = fminf(b3, t);
    }
    int gc = which * 16384 + b * NGG + m0;
    atomicMin(&colmin[gc + 0], fkey32(b0 + qq0));
    atomicMin(&colmin[gc + 1], fkey32(b1 + qq1));
    atomicMin(&colmin[gc + 2], fkey32(b2 + qq2));
    atomicMin(&colmin[gc + 3], fkey32(b3 + qq3));

  } else {
    // ------- argmin: pts vs gt candidates (keyed: dist<<32 | idx) -------
    int blk3 = blk - 1024;
    int qb = blk3 >> 4;          // [0,16)
    int seg = blk3 & 15;         // [0,16), 256 candidates each
    int b = qb >> 2;
    int m0 = (qb & 3) * 1024 + tid * 4;   // [0,4096)
    if (tid < 128) {
      const float* gtb = gt + (size_t)b * NGG * 6 + (size_t)seg * 256 * 6;
      int i0 = tid * 2;
      const float4* g4 = (const float4*)(gtb + (size_t)i0 * 6);
      float4 u0 = g4[0], u1 = g4[1], u2 = g4[2];
      sc[i0] = make_float4(u0.x, u0.y, u0.z,
                           fmaf(u0.x, u0.x, fmaf(u0.y, u0.y, u0.z * u0.z)));
      sc[i0 + 1] = make_float4(u1.z, u1.w, u2.x,
                               fmaf(u1.z, u1.z, fmaf(u1.w, u1.w, u2.x * u2.x)));
    }
    size_t fb = ((size_t)(b * NN + m0) * 3) >> 2;
    const float4* p4 = (const float4*)pts;
    float4 A = p4[fb], B = p4[fb + 1], C = p4[fb + 2];
    float q0x = A.x, q0y = A.y, q0z = A.z;
    float q1x = A.w, q1y = B.x, q1z = B.y;
    float q2x = B.z, q2y = B.w, q2z = C.x;
    float q3x = C.y, q3y = C.z, q3z = C.w;
    float a0x = -2.f * q0x, a0y = -2.f * q0y, a0z = -2.f * q0z;
    float a1x = -2.f * q1x, a1y = -2.f * q1y, a1z = -2.f * q1z;
    float a2x = -2.f * q2x, a2y = -2.f * q2y, a2z = -2.f * q2z;
    float a3x = -2.f * q3x, a3y = -2.f * q3y, a3z = -2.f * q3z;
    __syncthreads();
    float b0 = 3.4e38f, b1 = 3.4e38f, b2 = 3.4e38f, b3 = 3.4e38f;
    int i0 = 0, i1 = 0, i2 = 0, i3 = 0;
#pragma unroll 4
    for (int j = 0; j < 256; ++j) {
      float4 c = sc[j];
      float t; bool cc;
      t = fmaf(c.x, a0x, c.w); t = fmaf(c.y, a0y, t); t = fmaf(c.z, a0z, t);
      cc = t < b0; b0 = cc ? t : b0; i0 = cc ? j : i0;
      t = fmaf(c.x, a1x, c.w); t = fmaf(c.y, a1y, t); t = fmaf(c.z, a1z, t);
      cc = t < b1; b1 = cc ? t : b1; i1 = cc ? j : i1;
      t = fmaf(c.x, a2x, c.w); t = fmaf(c.y, a2y, t); t = fmaf(c.z, a2z, t);
      cc = t < b2; b2 = cc ? t : b2; i2 = cc ? j : i2;
      t = fmaf(c.x, a3x, c.w); t = fmaf(c.y, a3y, t); t = fmaf(c.z, a3z, t);
      cc = t < b3; b3 = cc ? t : b3; i3 = cc ? j : i3;
    }
    int q = b * NN + m0;
    int base = seg * 256;
    atomicMin(&keys[q + 0], ((unsigned long long)fkey32(b0) << 32) | (unsigned)(base + i0));
    atomicMin(&keys[q + 1], ((unsigned long long)fkey32(b1) << 32) | (unsigned)(base + i1));
    atomicMin(&keys[q + 2], ((unsigned long long)fkey32(b2) << 32) | (unsigned)(base + i2));
    atomicMin(&keys[q + 3], ((unsigned long long)fkey32(b3) << 32) | (unsigned)(base + i3));
  }
}

// ------------- postgather only (32 blocks x 512) -----------------------
__global__ __launch_bounds__(512) void k_post(
    const float* __restrict__ ori_pre, const float* __restrict__ nor_pre,
    const float* __restrict__ gt, const unsigned long long* __restrict__ keys,
    float* __restrict__ nor_gt, float* __restrict__ ori_pro, float* __restrict__ acc) {
  __shared__ float sb1[8], sb2[8];
  int q = blockIdx.x * 512 + threadIdx.x;    // [0,16384)
  int b = q >> 12;
  float ox = ori_pre[q * 3 + 0], oy = ori_pre[q * 3 + 1], oz = ori_pre[q * 3 + 2];
  float n1 = sqrtf(fmaf(ox, ox, fmaf(oy, oy, oz * oz)) + 1e-8f) + 1e-10f;
  ox /= n1; oy /= n1; oz /= n1;
  float px = nor_pre[q * 3 + 0], py = nor_pre[q * 3 + 1], pz = nor_pre[q * 3 + 2];
  float n2 = sqrtf(fmaf(px, px, fmaf(py, py, pz * pz)) + 1e-8f) + 1e-10f;
  px /= n2; py /= n2; pz /= n2;
  unsigned idx = (unsigned)(keys[q] & 0xffffffffULL);
  const float* g = gt + (size_t)b * NGG * 6 + (size_t)idx * 6 + 3;
  float gx = g[0], gy = g[1], gz = g[2];
  float dn = fmaf(gx, ox, fmaf(gy, oy, gz * oz));
  float vx = ox - gx * dn, vy = oy - gy * dn, vz = oz - gz * dn;
  float n3 = sqrtf(fmaf(vx, vx, fmaf(vy, vy, vz * vz)) + 1e-8f) + 1e-10f;
  vx /= n3; vy /= n3; vz /= n3;
  nor_gt[q * 3 + 0] = gx; nor_gt[q * 3 + 1] = gy; nor_gt[q * 3 + 2] = gz;
  ori_pro[q * 3 + 0] = vx; ori_pro[q * 3 + 1] = vy; ori_pro[q * 3 + 2] = vz;
  float na = fmaxf(sqrtf(fmaf(gx, gx, fmaf(gy, gy, gz * gz))), 1e-8f);
  float nb = fmaxf(sqrtf(fmaf(px, px, fmaf(py, py, pz * pz))), 1e-8f);
  float cs = fmaf(gx, px, fmaf(gy, py, gz * pz)) / (na * nb);
  float t_nor = 1.f - fabsf(cs);
  float t_ori = fabsf(dn);
  float s1 = block_sum_512(t_nor, sb1);
  float s2 = block_sum_512(t_ori, sb2);
  if (threadIdx.x == 0) {
    atomicAdd(&acc[1], s1);
    atomicAdd(&acc[2], s2);
  }
}

// ------------- KNN + smooth (blocks 0..1023) + min-reduces + finalize --
// blocks [0,1024): R2-proven knn-select + smooth epilogue (16 q/block,
//   32 lanes/q, shared-threshold pruning, tournament merge).
// blocks [1024,1152): rowmin reduce. blocks [1152,1216): colmin reduce.
// All blocks: done-counter in acc[9]; last block computes the 7 outputs.
__global__ __launch_bounds__(512) void k_knn_all(const float* __restrict__ pts,
                                                 const float* __restrict__ nor_gt,
                                                 const float* __restrict__ ori_pro,
                                                 const unsigned* __restrict__ rowmin,
                                                 const unsigned* __restrict__ colmin,
                                                 float* __restrict__ acc,
                                                 float* __restrict__ out) {
  __shared__ float4 sp[1152];    // 1024 + 128 pad = 18 KB
  __shared__ float sbuf[8];
  int tid = threadIdx.x;
  int blk = blockIdx.x;

  if (blk < 1024) {
    int q_local = tid >> 5;        // [0,16)
    int t = tid & 31;
    int q = blk * 16 + q_local;
    int b = q >> 12;
    int n = q & 4095;
    const float* pb = pts + (size_t)b * NN * 3;
    float qx = pb[n * 3 + 0], qy = pb[n * 3 + 1], qz = pb[n * 3 + 2];
    float qx2 = -2.f * qx, qy2 = -2.f * qy, qz2 = -2.f * qz;
    float d0 = 3.4e38f, d1 = 3.4e38f, d2 = 3.4e38f,
          d3 = 3.4e38f, d4 = 3.4e38f, d5 = 3.4e38f;
    int i0 = 0, i1 = 0, i2 = 0, i3 = 0, i4 = 0, i5 = 0;

    for (int ch = 0; ch < 4; ++ch) {
      if (tid < 256) {
        const float4* p4 = (const float4*)(pb + (size_t)(ch * 1024 + tid * 4) * 3);
        float4 u0 = p4[0], u1 = p4[1], u2 = p4[2];
        int il = tid * 4;
        int si = il + (il >> 3);   // pad-swizzle: kills 64B-stride conflicts
        sp[si] = make_float4(u0.x, u0.y, u0.z,
                             fmaf(u0.x, u0.x, fmaf(u0.y, u0.y, u0.z * u0.z)));
        sp[si + 1] = make_float4(u0.w, u1.x, u1.y,
                                 fmaf(u0.w, u0.w, fmaf(u1.x, u1.x, u1.y * u1.y)));
        sp[si + 2] = make_float4(u1.z, u1.w, u2.x,
                                 fmaf(u1.z, u1.z, fmaf(u1.w, u1.w, u2.x * u2.x)));
        sp[si + 3] = make_float4(u2.y, u2.z, u2.w,
                                 fmaf(u2.y, u2.y, fmaf(u2.z, u2.z, u2.w * u2.w)));
      }
      __syncthreads();
      int cbase = ch << 10;
      for (int jo = 0; jo < 4; ++jo) {
        // refresh shared threshold (stale-high is safe: only extra inserts)
        float T = d5;
#pragma unroll
        for (int o = 16; o > 0; o >>= 1) T = fminf(T, __shfl_xor(T, o, 32));
#pragma unroll
        for (int ji = 0; ji < 8; ++ji) {
          int c = (((jo << 3) | ji) << 5) | t;
          float4 p = sp[c + (c >> 3)];
          float d = fmaf(p.x, qx2, p.w);
          d = fmaf(p.y, qy2, d);
          d = fmaf(p.z, qz2, d);
          if (d <= T) {            // wave-rare: sorted insertion of (d, c)
            int ci = cbase | c;
            bool cc; float nd; int ni;
            cc = d < d0; nd = cc ? d : d0; d = cc ? d0 : d; ni = cc ? ci : i0; ci = cc ? i0 : ci; d0 = nd; i0 = ni;
            cc = d < d1; nd = cc ? d : d1; d = cc ? d1 : d; ni = cc ? ci : i1; ci = cc ? i1 : ci; d1 = nd; i1 = ni;
            cc = d < d2; nd = cc ? d : d2; d = cc ? d2 : d; ni = cc ? ci : i2; ci = cc ? i2 : ci; d2 = nd; i2 = ni;
            cc = d < d3; nd = cc ? d : d3; d = cc ? d3 : d; ni = cc ? ci : i3; ci = cc ? i3 : ci; d3 = nd; i3 = ni;
            cc = d < d4; nd = cc ? d : d4; d = cc ? d4 : d; ni = cc ? ci : i4; ci = cc ? i4 : ci; d4 = nd; i4 = ni;
            cc = d < d5; nd = cc ? d : d5;                  ni = cc ? ci : i5;                    d5 = nd; i5 = ni;
          }
        }
      }
      __syncthreads();
    }

    // 6-round tournament over 32 per-lane sorted lists (u64 keys unique)
    int myid = 0;
#pragma unroll
    for (int r = 0; r < 6; ++r) {
      unsigned long long h = ((unsigned long long)fkey32(d0) << 32) | (unsigned)i0;
      unsigned long long m = h;
#pragma unroll
      for (int o = 16; o > 0; o >>= 1) {
        unsigned long long other = __shfl_xor(m, o, 32);
        m = (other < m) ? other : m;
      }
      if (t == r) myid = (int)(m & 0xffffffffULL);
      if (h == m) {   // this lane won round r: pop head
        d0 = d1; i0 = i1; d1 = d2; i1 = i2; d2 = d3; i2 = i3;
        d3 = d4; i3 = i4; d4 = d5; i4 = i5; d5 = 3.4e38f;
      }
    }

    float sum = 0.f;
    if (t < 6) {
      const float* gq = nor_gt + (size_t)q * 3;
      float ngx = gq[0], ngy = gq[1], ngz = gq[2];
      const float* oq = ori_pro + (size_t)q * 3;
      float box = oq[0], boy = oq[1], boz = oq[2];
      float rx = boy * ngz - boz * ngy;
      float ry = boz * ngx - box * ngz;
      float rz = box * ngy - boy * ngx;
      float nbo = fmaxf(sqrtf(fmaf(box, box, fmaf(boy, boy, boz * boz))), 1e-8f);
      float nrot = fmaxf(sqrtf(fmaf(rx, rx, fmaf(ry, ry, rz * rz))), 1e-8f);
      const float* gn = nor_gt + (size_t)(b * 4096 + myid) * 3;
      const float* go = ori_pro + (size_t)(b * 4096 + myid) * 3;
      float gnx = gn[0], gny = gn[1], gnz = gn[2];
      float gox = go[0], goy = go[1], goz = go[2];
      float ndv = fmaf(gnx, ngx, fmaf(gny, ngy, gnz * ngz));
      float wv = (expf(-ndv / 0.3f) * 10.f + 1.f) < 4.f ? 1.f : 5.f;
      float ngo = fmaxf(sqrtf(fmaf(gox, gox, fmaf(goy, goy, goz * goz))), 1e-8f);
      float c0 = fmaf(gox, box, fmaf(goy, boy, goz * boz)) / (ngo * nbo);
      float c1 = fmaf(gox, rx, fmaf(goy, ry, goz * rz)) / (ngo * nrot);
      float cosv = fminf(1.f - fabsf(c0), 1.f - fabsf(c1));
      sum = wv * cosv;
    }
    float s = block_sum_512(sum, sbuf);
    if (tid == 0) atomicAdd(&acc[0], s);

  } else if (blk < 1152) {
    int i = (blk - 1024) * 512 + tid;     // [0,65536)
    float v = unfkey32(rowmin[i]);
    int slot = (i >> 15) ? 5 : 3;         // block-uniform (32768/512 = 64)
    float s = block_sum_512(v, sbuf);
    if (tid == 0) atomicAdd(&acc[slot], s);
  } else {
    int i = (blk - 1152) * 512 + tid;     // [0,32768)
    float v = unfkey32(colmin[i]);
    int slot = (i >> 14) ? 6 : 4;         // block-uniform (16384/512 = 32)
    float s = block_sum_512(v, sbuf);
    if (tid == 0) atomicAdd(&acc[slot], s);
  }

  // ---- finalize: last block to finish computes the 7 outputs ----
  __threadfence();
  if (tid == 0) {
    unsigned c = atomicAdd((unsigned*)(acc + 9), 1u);
    if (c == gridDim.x - 1) {
      __threadfence();
      float a0 = atomicAdd(&acc[0], 0.f);
      float a1 = atomicAdd(&acc[1], 0.f);
      float a2 = atomicAdd(&acc[2], 0.f);
      float a3 = atomicAdd(&acc[3], 0.f);
      float a4 = atomicAdd(&acc[4], 0.f);
      float a5 = atomicAdd(&acc[5], 0.f);
      float a6 = atomicAdd(&acc[6], 0.f);
      float loss_smooth = a0 / 98304.f;            // B*N*K
      float loss_nor = a1 / 16384.f;               // B*N
      float loss_nor_ori = a2 / 16384.f;
      float lco = a3 / 32768.f + a4 / 16384.f;     // B*NU rows + B*NG cols
      float lc = a5 / 32768.f + a6 / 16384.f;
      float loss_cd = lc + 0.4f * lco;
      float loss = loss_smooth + loss_nor + 0.1f * loss_nor_ori + 200.f * loss_cd;
      out[0] = loss;
      out[1] = loss_smooth;
      out[2] = loss_nor;
      out[3] = lco;
      out[4] = loss_nor_ori;
      out[5] = lc;
      out[6] = lc;
    }
  }
}

extern "C" void kernel_launch(void* const* d_in, const int* in_sizes, int n_in,
                              void* d_out, int out_size, void* d_ws, size_t ws_size,
                              hipStream_t stream) {
  (void)in_sizes; (void)n_in; (void)out_size; (void)ws_size;
  const float* ori_pre = (const float*)d_in[0];
  const float* nor_pre = (const float*)d_in[1];
  const float* xyz_up = (const float*)d_in[2];
  const float* xyz_off = (const float*)d_in[3];
  const float* pts = (const float*)d_in[4];
  const float* gt = (const float*)d_in[5];
  float* out = (float*)d_out;
  char* ws = (char*)d_ws;

  float* acc = (float*)(ws + 0);                                   // 16 floats: 0..6 sums, 9 done ctr
  unsigned long long* keys = (unsigned long long*)(ws + 512);      // 16384 u64 = 128 KB
  unsigned* rowmin = (unsigned*)(ws + 512 + 131072);               // 65536 u32 = 256 KB
  unsigned* colmin = (unsigned*)(ws + 512 + 131072 + 262144);      // 32768 u32 = 128 KB
  float* nor_gt = (float*)(ws + 512 + 131072 + 262144 + 131072);   // 49152 f32 = 192 KB
  float* ori_pro = (float*)(ws + 512 + 131072 + 262144 + 131072 + 196608);

  hipMemsetAsync(ws + 512, 0xFF, 131072 + 262144 + 131072, stream);

  k_scan<<<1280, 256, 0, stream>>>(pts, gt, xyz_up, xyz_off, keys, rowmin,
                                   colmin, acc);
  k_post<<<32, 512, 0, stream>>>(ori_pre, nor_pre, gt, keys, nor_gt, ori_pro, acc);
  k_knn_all<<<1216, 512, 0, stream>>>(pts, nor_gt, ori_pro, rowmin, colmin,
                                      acc, out);
}

// Round 8
// 198.470 us; speedup vs baseline: 1.4949x; 1.4949x over previous
//
#include <hip/hip_runtime.h>
#include <stdint.h>

#define NN 4096
#define NGG 4096
#define NUU 8192

// monotone float->uint mapping (order-preserving incl. negatives)
__device__ __forceinline__ unsigned fkey32(float f) {
  unsigned u = __float_as_uint(f);
  return u ^ (((int)u >> 31) | 0x80000000u);
}
__device__ __forceinline__ float unfkey32(unsigned k) {
  unsigned m = (k & 0x80000000u) ? 0x80000000u : 0xFFFFFFFFu;
  return __uint_as_float(k ^ m);
}

// ---------------- block-wide sum (blockDim.x == 256) -------------------
__device__ __forceinline__ float block_sum_256(float v, float* sbuf) {
#pragma unroll
  for (int o = 32; o > 0; o >>= 1) v += __shfl_down(v, o, 64);
  int lane = threadIdx.x & 63;
  int w = threadIdx.x >> 6;
  if (lane == 0) sbuf[w] = v;
  __syncthreads();
  float r = 0.f;
  if (threadIdx.x == 0) r = sbuf[0] + sbuf[1] + sbuf[2] + sbuf[3];
  __syncthreads();
  return r;
}

// ---------------- block-wide sum (blockDim.x == 512) -------------------
__device__ __forceinline__ float block_sum_512(float v, float* sbuf) {
#pragma unroll
  for (int o = 32; o > 0; o >>= 1) v += __shfl_down(v, o, 64);
  int lane = threadIdx.x & 63;
  int w = threadIdx.x >> 6;
  if (lane == 0) sbuf[w] = v;
  __syncthreads();
  float r = 0.f;
  if (threadIdx.x == 0) {
#pragma unroll
    for (int i = 0; i < 8; ++i) r += sbuf[i];
  }
  __syncthreads();
  return r;
}

// ---------------- fused scan: argmin + chamfer rows + chamfer cols -----
// R2-proven layout (Q=4, 1280 blocks, 256 thr). Block 0 zeroes acc
// (replaces the acc memset; acc is only consumed by later kernels in the
// same stream).
// blocks [0,512): cham_row  (65536 queries, gt candidates, 8 segs x 512)
// blocks [512,1024): cham_col (32768 queries, up/off candidates, 16 segs x 512)
// blocks [1024,1280): argmin (16384 queries, gt candidates, 16 segs x 256)
__global__ __launch_bounds__(256) void k_scan(const float* __restrict__ pts,
                                              const float* __restrict__ gt,
                                              const float* __restrict__ up,
                                              const float* __restrict__ off,
                                              unsigned long long* __restrict__ keys,
                                              unsigned* __restrict__ rowmin,
                                              unsigned* __restrict__ colmin,
                                              float* __restrict__ acc) {
  __shared__ float4 sc[512];   // 8 KB
  int blk = blockIdx.x;
  int tid = threadIdx.x;
  if (blk == 0 && tid < 16) acc[tid] = 0.f;

  if (blk < 512) {
    // ------- cham_row: up/off points vs gt candidates -------
    int qb = blk >> 3;           // [0,64)
    int seg = blk & 7;           // [0,8)
    int wb = qb >> 3;            // [0,8)
    int which = wb >> 2;         // 0=off, 1=up
    int b = wb & 3;
    int r0 = (qb & 7) * 1024 + tid * 4;   // [0,8192)
    {
      const float* gtb = gt + (size_t)b * NGG * 6 + (size_t)seg * 512 * 6;
      int i0 = tid * 2;
      const float4* g4 = (const float4*)(gtb + (size_t)i0 * 6);
      float4 u0 = g4[0], u1 = g4[1], u2 = g4[2];
      sc[i0] = make_float4(u0.x, u0.y, u0.z,
                           fmaf(u0.x, u0.x, fmaf(u0.y, u0.y, u0.z * u0.z)));
      sc[i0 + 1] = make_float4(u1.z, u1.w, u2.x,
                               fmaf(u1.z, u1.z, fmaf(u1.w, u1.w, u2.x * u2.x)));
    }
    const float* src = which ? up : off;
    const float4* s4 = (const float4*)src;
    size_t fb = ((size_t)(b * NUU + r0) * 3) >> 2;
    float4 A = s4[fb], B = s4[fb + 1], C = s4[fb + 2];
    float q0x = A.x, q0y = A.y, q0z = A.z;
    float q1x = A.w, q1y = B.x, q1z = B.y;
    float q2x = B.z, q2y = B.w, q2z = C.x;
    float q3x = C.y, q3y = C.z, q3z = C.w;
    float qq0 = fmaf(q0x, q0x, fmaf(q0y, q0y, q0z * q0z));
    float qq1 = fmaf(q1x, q1x, fmaf(q1y, q1y, q1z * q1z));
    float qq2 = fmaf(q2x, q2x, fmaf(q2y, q2y, q2z * q2z));
    float qq3 = fmaf(q3x, q3x, fmaf(q3y, q3y, q3z * q3z));
    float a0x = -2.f * q0x, a0y = -2.f * q0y, a0z = -2.f * q0z;
    float a1x = -2.f * q1x, a1y = -2.f * q1y, a1z = -2.f * q1z;
    float a2x = -2.f * q2x, a2y = -2.f * q2y, a2z = -2.f * q2z;
    float a3x = -2.f * q3x, a3y = -2.f * q3y, a3z = -2.f * q3z;
    __syncthreads();
    float b0 = 3.4e38f, b1 = 3.4e38f, b2 = 3.4e38f, b3 = 3.4e38f;
#pragma unroll 4
    for (int j = 0; j < 512; ++j) {
      float4 c = sc[j];
      float t;
      t = fmaf(c.x, a0x, c.w); t = fmaf(c.y, a0y, t); t = fmaf(c.z, a0z, t); b0 = fminf(b0, t);
      t = fmaf(c.x, a1x, c.w); t = fmaf(c.y, a1y, t); t = fmaf(c.z, a1z, t); b1 = fminf(b1, t);
      t = fmaf(c.x, a2x, c.w); t = fmaf(c.y, a2y, t); t = fmaf(c.z, a2z, t); b2 = fminf(b2, t);
      t = fmaf(c.x, a3x, c.w); t = fmaf(c.y, a3y, t); t = fmaf(c.z, a3z, t); b3 = fminf(b3, t);
    }
    int gr = which * 32768 + b * NUU + r0;
    atomicMin(&rowmin[gr + 0], fkey32(b0 + qq0));
    atomicMin(&rowmin[gr + 1], fkey32(b1 + qq1));
    atomicMin(&rowmin[gr + 2], fkey32(b2 + qq2));
    atomicMin(&rowmin[gr + 3], fkey32(b3 + qq3));

  } else if (blk < 1024) {
    // ------- cham_col: gt points vs up/off candidates -------
    int blk2 = blk - 512;
    int qb = blk2 >> 4;          // [0,32)
    int seg = blk2 & 15;         // [0,16)
    int which = qb >> 4;         // 0=off, 1=up
    int b = (qb >> 2) & 3;
    int m0 = (qb & 3) * 1024 + tid * 4;   // [0,4096)
    const float* src = which ? up : off;
    if (tid < 128) {
      const float* sb = src + (size_t)b * NUU * 3 + (size_t)seg * 512 * 3;
      int i0 = tid * 4;
      const float4* s4 = (const float4*)(sb + (size_t)i0 * 3);
      float4 u0 = s4[0], u1 = s4[1], u2 = s4[2];
      sc[i0] = make_float4(u0.x, u0.y, u0.z,
                           fmaf(u0.x, u0.x, fmaf(u0.y, u0.y, u0.z * u0.z)));
      sc[i0 + 1] = make_float4(u0.w, u1.x, u1.y,
                               fmaf(u0.w, u0.w, fmaf(u1.x, u1.x, u1.y * u1.y)));
      sc[i0 + 2] = make_float4(u1.z, u1.w, u2.x,
                               fmaf(u1.z, u1.z, fmaf(u1.w, u1.w, u2.x * u2.x)));
      sc[i0 + 3] = make_float4(u2.y, u2.z, u2.w,
                               fmaf(u2.y, u2.y, fmaf(u2.z, u2.z, u2.w * u2.w)));
    }
    const float* g = gt + (size_t)b * NGG * 6 + (size_t)m0 * 6;
    float q0x = g[0],  q0y = g[1],  q0z = g[2];
    float q1x = g[6],  q1y = g[7],  q1z = g[8];
    float q2x = g[12], q2y = g[13], q2z = g[14];
    float q3x = g[18], q3y = g[19], q3z = g[20];
    float qq0 = fmaf(q0x, q0x, fmaf(q0y, q0y, q0z * q0z));
    float qq1 = fmaf(q1x, q1x, fmaf(q1y, q1y, q1z * q1z));
    float qq2 = fmaf(q2x, q2x, fmaf(q2y, q2y, q2z * q2z));
    float qq3 = fmaf(q3x, q3x, fmaf(q3y, q3y, q3z * q3z));
    float a0x = -2.f * q0x, a0y = -2.f * q0y, a0z = -2.f * q0z;
    float a1x = -2.f * q1x, a1y = -2.f * q1y, a1z = -2.f * q1z;
    float a2x = -2.f * q2x, a2y = -2.f * q2y, a2z = -2.f * q2z;
    float a3x = -2.f * q3x, a3y = -2.f * q3y, a3z = -2.f * q3z;
    __syncthreads();
    float b0 = 3.4e38f, b1 = 3.4e38f, b2 = 3.4e38f, b3 = 3.4e38f;
#pragma unroll 4
    for (int j = 0; j < 512; ++j) {
      float4 c = sc[j];
      float t;
      t = fmaf(c.x, a0x, c.w); t = fmaf(c.y, a0y, t); t = fmaf(c.z, a0z, t); b0 = fminf(b0, t);
      t = fmaf(c.x, a1x, c.w); t = fmaf(c.y, a1y, t); t = fmaf(c.z, a1z, t); b1 = fminf(b1, t);
      t = fmaf(c.x, a2x, c.w); t = fmaf(c.y, a2y, t); t = fmaf(c.z, a2z, t); b2 = fminf(b2, t);
      t = fmaf(c.x, a3x, c.w); t = fmaf(c.y, a3y, t); t = fmaf(c.z, a3z, t); b3 = fminf(b3, t);
    }
    int gc = which * 16384 + b * NGG + m0;
    atomicMin(&colmin[gc + 0], fkey32(b0 + qq0));
    atomicMin(&colmin[gc + 1], fkey32(b1 + qq1));
    atomicMin(&colmin[gc + 2], fkey32(b2 + qq2));
    atomicMin(&colmin[gc + 3], fkey32(b3 + qq3));

  } else {
    // ------- argmin: pts vs gt candidates (keyed: dist<<32 | idx) -------
    int blk3 = blk - 1024;
    int qb = blk3 >> 4;          // [0,16)
    int seg = blk3 & 15;         // [0,16), 256 candidates each
    int b = qb >> 2;
    int m0 = (qb & 3) * 1024 + tid * 4;   // [0,4096)
    if (tid < 128) {
      const float* gtb = gt + (size_t)b * NGG * 6 + (size_t)seg * 256 * 6;
      int i0 = tid * 2;
      const float4* g4 = (const float4*)(gtb + (size_t)i0 * 6);
      float4 u0 = g4[0], u1 = g4[1], u2 = g4[2];
      sc[i0] = make_float4(u0.x, u0.y, u0.z,
                           fmaf(u0.x, u0.x, fmaf(u0.y, u0.y, u0.z * u0.z)));
      sc[i0 + 1] = make_float4(u1.z, u1.w, u2.x,
                               fmaf(u1.z, u1.z, fmaf(u1.w, u1.w, u2.x * u2.x)));
    }
    size_t fb = ((size_t)(b * NN + m0) * 3) >> 2;
    const float4* p4 = (const float4*)pts;
    float4 A = p4[fb], B = p4[fb + 1], C = p4[fb + 2];
    float q0x = A.x, q0y = A.y, q0z = A.z;
    float q1x = A.w, q1y = B.x, q1z = B.y;
    float q2x = B.z, q2y = B.w, q2z = C.x;
    float q3x = C.y, q3y = C.z, q3z = C.w;
    float a0x = -2.f * q0x, a0y = -2.f * q0y, a0z = -2.f * q0z;
    float a1x = -2.f * q1x, a1y = -2.f * q1y, a1z = -2.f * q1z;
    float a2x = -2.f * q2x, a2y = -2.f * q2y, a2z = -2.f * q2z;
    float a3x = -2.f * q3x, a3y = -2.f * q3y, a3z = -2.f * q3z;
    __syncthreads();
    float b0 = 3.4e38f, b1 = 3.4e38f, b2 = 3.4e38f, b3 = 3.4e38f;
    int i0 = 0, i1 = 0, i2 = 0, i3 = 0;
#pragma unroll 4
    for (int j = 0; j < 256; ++j) {
      float4 c = sc[j];
      float t; bool cc;
      t = fmaf(c.x, a0x, c.w); t = fmaf(c.y, a0y, t); t = fmaf(c.z, a0z, t);
      cc = t < b0; b0 = cc ? t : b0; i0 = cc ? j : i0;
      t = fmaf(c.x, a1x, c.w); t = fmaf(c.y, a1y, t); t = fmaf(c.z, a1z, t);
      cc = t < b1; b1 = cc ? t : b1; i1 = cc ? j : i1;
      t = fmaf(c.x, a2x, c.w); t = fmaf(c.y, a2y, t); t = fmaf(c.z, a2z, t);
      cc = t < b2; b2 = cc ? t : b2; i2 = cc ? j : i2;
      t = fmaf(c.x, a3x, c.w); t = fmaf(c.y, a3y, t); t = fmaf(c.z, a3z, t);
      cc = t < b3; b3 = cc ? t : b3; i3 = cc ? j : i3;
    }
    int q = b * NN + m0;
    int base = seg * 256;
    atomicMin(&keys[q + 0], ((unsigned long long)fkey32(b0) << 32) | (unsigned)(base + i0));
    atomicMin(&keys[q + 1], ((unsigned long long)fkey32(b1) << 32) | (unsigned)(base + i1));
    atomicMin(&keys[q + 2], ((unsigned long long)fkey32(b2) << 32) | (unsigned)(base + i2));
    atomicMin(&keys[q + 3], ((unsigned long long)fkey32(b3) << 32) | (unsigned)(base + i3));
  }
}

// ------------- fused: postgather (blocks 0..63) + reduce mins (64..447) -
// R2-proven verbatim.
__global__ __launch_bounds__(256) void k_post(
    const float* __restrict__ ori_pre, const float* __restrict__ nor_pre,
    const float* __restrict__ gt, const unsigned long long* __restrict__ keys,
    const unsigned* __restrict__ rowmin, const unsigned* __restrict__ colmin,
    float* __restrict__ nor_gt, float* __restrict__ ori_pro, float* __restrict__ acc) {
  __shared__ float sb1[4], sb2[4];
  int blk = blockIdx.x;
  if (blk < 64) {
    int q = blk * 256 + threadIdx.x;
    int b = q >> 12;
    float ox = ori_pre[q * 3 + 0], oy = ori_pre[q * 3 + 1], oz = ori_pre[q * 3 + 2];
    float n1 = sqrtf(fmaf(ox, ox, fmaf(oy, oy, oz * oz)) + 1e-8f) + 1e-10f;
    ox /= n1; oy /= n1; oz /= n1;
    float px = nor_pre[q * 3 + 0], py = nor_pre[q * 3 + 1], pz = nor_pre[q * 3 + 2];
    float n2 = sqrtf(fmaf(px, px, fmaf(py, py, pz * pz)) + 1e-8f) + 1e-10f;
    px /= n2; py /= n2; pz /= n2;
    unsigned idx = (unsigned)(keys[q] & 0xffffffffULL);
    const float* g = gt + (size_t)b * NGG * 6 + (size_t)idx * 6 + 3;
    float gx = g[0], gy = g[1], gz = g[2];
    float dn = fmaf(gx, ox, fmaf(gy, oy, gz * oz));
    float vx = ox - gx * dn, vy = oy - gy * dn, vz = oz - gz * dn;
    float n3 = sqrtf(fmaf(vx, vx, fmaf(vy, vy, vz * vz)) + 1e-8f) + 1e-10f;
    vx /= n3; vy /= n3; vz /= n3;
    nor_gt[q * 3 + 0] = gx; nor_gt[q * 3 + 1] = gy; nor_gt[q * 3 + 2] = gz;
    ori_pro[q * 3 + 0] = vx; ori_pro[q * 3 + 1] = vy; ori_pro[q * 3 + 2] = vz;
    float na = fmaxf(sqrtf(fmaf(gx, gx, fmaf(gy, gy, gz * gz))), 1e-8f);
    float nb = fmaxf(sqrtf(fmaf(px, px, fmaf(py, py, pz * pz))), 1e-8f);
    float cs = fmaf(gx, px, fmaf(gy, py, gz * pz)) / (na * nb);
    float t_nor = 1.f - fabsf(cs);
    float t_ori = fabsf(dn);
    float s1 = block_sum_256(t_nor, sb1);
    float s2 = block_sum_256(t_ori, sb2);
    if (threadIdx.x == 0) {
      atomicAdd(&acc[1], s1);
      atomicAdd(&acc[2], s2);
    }
  } else {
    int rblk = blk - 64;   // [0,384)
    float v;
    int slot;
    if (rblk < 256) {
      int i = rblk * 256 + threadIdx.x;
      v = unfkey32(rowmin[i]);
      slot = (i >> 15) ? 5 : 3;   // 0=offset rows -> acc3, 1=up rows -> acc5
    } else {
      int i = (rblk - 256) * 256 + threadIdx.x;
      v = unfkey32(colmin[i]);
      slot = (i >> 14) ? 6 : 4;   // 0=offset cols -> acc4, 1=up cols -> acc6
    }
    float s = block_sum_256(v, sb1);
    if (threadIdx.x == 0) atomicAdd(&acc[slot], s);
  }
}

// ------------- KNN (K=6) + fused loss_smooth + last-block finalize -----
// R2-proven knn/smooth body (1024 blocks x 512, 16 q/block, 32 lanes/q).
// Finalize: done-counter in acc[9]; fence + atomics by tid==0 ONLY
// (R7's all-thread __threadfence was the 2.6x stall suspect).
__global__ __launch_bounds__(512) void k_knn_smooth(const float* __restrict__ pts,
                                                    const float* __restrict__ nor_gt,
                                                    const float* __restrict__ ori_pro,
                                                    float* __restrict__ acc,
                                                    float* __restrict__ out) {
  __shared__ float4 sp[1152];    // 1024 + 128 pad = 18 KB
  __shared__ float sbuf[8];
  int tid = threadIdx.x;
  int q_local = tid >> 5;        // [0,16)
  int t = tid & 31;
  int q = blockIdx.x * 16 + q_local;
  int b = q >> 12;
  int n = q & 4095;
  const float* pb = pts + (size_t)b * NN * 3;
  float qx = pb[n * 3 + 0], qy = pb[n * 3 + 1], qz = pb[n * 3 + 2];
  float qx2 = -2.f * qx, qy2 = -2.f * qy, qz2 = -2.f * qz;
  float d0 = 3.4e38f, d1 = 3.4e38f, d2 = 3.4e38f,
        d3 = 3.4e38f, d4 = 3.4e38f, d5 = 3.4e38f;
  int i0 = 0, i1 = 0, i2 = 0, i3 = 0, i4 = 0, i5 = 0;

  for (int ch = 0; ch < 4; ++ch) {
    if (tid < 256) {
      const float4* p4 = (const float4*)(pb + (size_t)(ch * 1024 + tid * 4) * 3);
      float4 u0 = p4[0], u1 = p4[1], u2 = p4[2];
      int il = tid * 4;
      int si = il + (il >> 3);   // pad-swizzle: kills 64B-stride conflicts
      sp[si] = make_float4(u0.x, u0.y, u0.z,
                           fmaf(u0.x, u0.x, fmaf(u0.y, u0.y, u0.z * u0.z)));
      sp[si + 1] = make_float4(u0.w, u1.x, u1.y,
                               fmaf(u0.w, u0.w, fmaf(u1.x, u1.x, u1.y * u1.y)));
      sp[si + 2] = make_float4(u1.z, u1.w, u2.x,
                               fmaf(u1.z, u1.z, fmaf(u1.w, u1.w, u2.x * u2.x)));
      sp[si + 3] = make_float4(u2.y, u2.z, u2.w,
                               fmaf(u2.y, u2.y, fmaf(u2.z, u2.z, u2.w * u2.w)));
    }
    __syncthreads();
    int cbase = ch << 10;
    for (int jo = 0; jo < 4; ++jo) {
      // refresh shared threshold (stale-high is safe: only extra inserts)
      float T = d5;
#pragma unroll
      for (int o = 16; o > 0; o >>= 1) T = fminf(T, __shfl_xor(T, o, 32));
#pragma unroll
      for (int ji = 0; ji < 8; ++ji) {
        int c = (((jo << 3) | ji) << 5) | t;
        float4 p = sp[c + (c >> 3)];
        float d = fmaf(p.x, qx2, p.w);
        d = fmaf(p.y, qy2, d);
        d = fmaf(p.z, qz2, d);
        if (d <= T) {            // wave-rare: sorted insertion of (d, c)
          int ci = cbase | c;
          bool cc; float nd; int ni;
          cc = d < d0; nd = cc ? d : d0; d = cc ? d0 : d; ni = cc ? ci : i0; ci = cc ? i0 : ci; d0 = nd; i0 = ni;
          cc = d < d1; nd = cc ? d : d1; d = cc ? d1 : d; ni = cc ? ci : i1; ci = cc ? i1 : ci; d1 = nd; i1 = ni;
          cc = d < d2; nd = cc ? d : d2; d = cc ? d2 : d; ni = cc ? ci : i2; ci = cc ? i2 : ci; d2 = nd; i2 = ni;
          cc = d < d3; nd = cc ? d : d3; d = cc ? d3 : d; ni = cc ? ci : i3; ci = cc ? i3 : ci; d3 = nd; i3 = ni;
          cc = d < d4; nd = cc ? d : d4; d = cc ? d4 : d; ni = cc ? ci : i4; ci = cc ? i4 : ci; d4 = nd; i4 = ni;
          cc = d < d5; nd = cc ? d : d5;                  ni = cc ? ci : i5;                    d5 = nd; i5 = ni;
        }
      }
    }
    __syncthreads();
  }

  // 6-round tournament over the 32 per-lane sorted lists (keys unique:
  // idx disambiguates; a lane pops at most 6 times so heads stay real).
  int myid = 0;
#pragma unroll
  for (int r = 0; r < 6; ++r) {
    unsigned long long h = ((unsigned long long)fkey32(d0) << 32) | (unsigned)i0;
    unsigned long long m = h;
#pragma unroll
    for (int o = 16; o > 0; o >>= 1) {
      unsigned long long other = __shfl_xor(m, o, 32);
      m = (other < m) ? other : m;
    }
    if (t == r) myid = (int)(m & 0xffffffffULL);
    if (h == m) {   // this lane won round r: pop head
      d0 = d1; i0 = i1; d1 = d2; i1 = i2; d2 = d3; i2 = i3;
      d3 = d4; i3 = i4; d4 = d5; i4 = i5; d5 = 3.4e38f;
    }
  }

  float sum = 0.f;
  if (t < 6) {
    const float* gq = nor_gt + (size_t)q * 3;
    float ngx = gq[0], ngy = gq[1], ngz = gq[2];
    const float* oq = ori_pro + (size_t)q * 3;
    float box = oq[0], boy = oq[1], boz = oq[2];
    float rx = boy * ngz - boz * ngy;
    float ry = boz * ngx - box * ngz;
    float rz = box * ngy - boy * ngx;
    float nbo = fmaxf(sqrtf(fmaf(box, box, fmaf(boy, boy, boz * boz))), 1e-8f);
    float nrot = fmaxf(sqrtf(fmaf(rx, rx, fmaf(ry, ry, rz * rz))), 1e-8f);
    const float* gn = nor_gt + (size_t)(b * 4096 + myid) * 3;
    const float* go = ori_pro + (size_t)(b * 4096 + myid) * 3;
    float gnx = gn[0], gny = gn[1], gnz = gn[2];
    float gox = go[0], goy = go[1], goz = go[2];
    float ndv = fmaf(gnx, ngx, fmaf(gny, ngy, gnz * ngz));
    float wv = (expf(-ndv / 0.3f) * 10.f + 1.f) < 4.f ? 1.f : 5.f;
    float ngo = fmaxf(sqrtf(fmaf(gox, gox, fmaf(goy, goy, goz * goz))), 1e-8f);
    float c0 = fmaf(gox, box, fmaf(goy, boy, goz * boz)) / (ngo * nbo);
    float c1 = fmaf(gox, rx, fmaf(goy, ry, goz * rz)) / (ngo * nrot);
    float cosv = fminf(1.f - fabsf(c0), 1.f - fabsf(c1));
    sum = wv * cosv;
  }
  float s = block_sum_512(sum, sbuf);

  // ---- finalize: tid 0 only (fence count = gridDim, not threads) ----
  if (tid == 0) {
    atomicAdd(&acc[0], s);
    __threadfence();
    unsigned c = atomicAdd((unsigned*)(acc + 9), 1u);
    if (c == gridDim.x - 1) {
      __threadfence();
      float a0 = atomicAdd(&acc[0], 0.f);
      float a1 = atomicAdd(&acc[1], 0.f);
      float a2 = atomicAdd(&acc[2], 0.f);
      float a3 = atomicAdd(&acc[3], 0.f);
      float a4 = atomicAdd(&acc[4], 0.f);
      float a5 = atomicAdd(&acc[5], 0.f);
      float a6 = atomicAdd(&acc[6], 0.f);
      float loss_smooth = a0 / 98304.f;            // B*N*K
      float loss_nor = a1 / 16384.f;               // B*N
      float loss_nor_ori = a2 / 16384.f;
      float lco = a3 / 32768.f + a4 / 16384.f;     // B*NU rows + B*NG cols
      float lc = a5 / 32768.f + a6 / 16384.f;
      float loss_cd = lc + 0.4f * lco;
      float loss = loss_smooth + loss_nor + 0.1f * loss_nor_ori + 200.f * loss_cd;
      out[0] = loss;
      out[1] = loss_smooth;
      out[2] = loss_nor;
      out[3] = lco;
      out[4] = loss_nor_ori;
      out[5] = lc;
      out[6] = lc;
    }
  }
}

extern "C" void kernel_launch(void* const* d_in, const int* in_sizes, int n_in,
                              void* d_out, int out_size, void* d_ws, size_t ws_size,
                              hipStream_t stream) {
  (void)in_sizes; (void)n_in; (void)out_size; (void)ws_size;
  const float* ori_pre = (const float*)d_in[0];
  const float* nor_pre = (const float*)d_in[1];
  const float* xyz_up = (const float*)d_in[2];
  const float* xyz_off = (const float*)d_in[3];
  const float* pts = (const float*)d_in[4];
  const float* gt = (const float*)d_in[5];
  float* out = (float*)d_out;
  char* ws = (char*)d_ws;

  float* acc = (float*)(ws + 0);                                   // 16 floats: 0..6 sums, 9 done ctr
  unsigned long long* keys = (unsigned long long*)(ws + 512);      // 16384 u64 = 128 KB
  unsigned* rowmin = (unsigned*)(ws + 512 + 131072);               // 65536 u32 = 256 KB
  unsigned* colmin = (unsigned*)(ws + 512 + 131072 + 262144);      // 32768 u32 = 128 KB
  float* nor_gt = (float*)(ws + 512 + 131072 + 262144 + 131072);   // 49152 f32 = 192 KB
  float* ori_pro = (float*)(ws + 512 + 131072 + 262144 + 131072 + 196608);

  hipMemsetAsync(ws + 512, 0xFF, 131072 + 262144 + 131072, stream);

  k_scan<<<1280, 256, 0, stream>>>(pts, gt, xyz_up, xyz_off, keys, rowmin,
                                   colmin, acc);
  k_post<<<448, 256, 0, stream>>>(ori_pre, nor_pre, gt, keys, rowmin, colmin,
                                  nor_gt, ori_pro, acc);
  k_knn_smooth<<<1024, 512, 0, stream>>>(pts, nor_gt, ori_pro, acc, out);
}

// Round 9
// 194.101 us; speedup vs baseline: 1.5286x; 1.0225x over previous
//
#include <hip/hip_runtime.h>
#include <stdint.h>

#define NN 4096
#define NGG 4096
#define NUU 8192

// monotone float->uint mapping (order-preserving incl. negatives)
__device__ __forceinline__ unsigned fkey32(float f) {
  unsigned u = __float_as_uint(f);
  return u ^ (((int)u >> 31) | 0x80000000u);
}
__device__ __forceinline__ float unfkey32(unsigned k) {
  unsigned m = (k & 0x80000000u) ? 0x80000000u : 0xFFFFFFFFu;
  return __uint_as_float(k ^ m);
}

// ---------------- block-wide sum (blockDim.x == 256) -------------------
__device__ __forceinline__ float block_sum_256(float v, float* sbuf) {
#pragma unroll
  for (int o = 32; o > 0; o >>= 1) v += __shfl_down(v, o, 64);
  int lane = threadIdx.x & 63;
  int w = threadIdx.x >> 6;
  if (lane == 0) sbuf[w] = v;
  __syncthreads();
  float r = 0.f;
  if (threadIdx.x == 0) r = sbuf[0] + sbuf[1] + sbuf[2] + sbuf[3];
  __syncthreads();
  return r;
}

// ---------------- block-wide sum (blockDim.x == 512) -------------------
__device__ __forceinline__ float block_sum_512(float v, float* sbuf) {
#pragma unroll
  for (int o = 32; o > 0; o >>= 1) v += __shfl_down(v, o, 64);
  int lane = threadIdx.x & 63;
  int w = threadIdx.x >> 6;
  if (lane == 0) sbuf[w] = v;
  __syncthreads();
  float r = 0.f;
  if (threadIdx.x == 0) {
#pragma unroll
    for (int i = 0; i < 8; ++i) r += sbuf[i];
  }
  __syncthreads();
  return r;
}

// ---------------- fused scan: argmin + chamfer rows + chamfer cols -----
// R2-proven layout (Q=4, 1280 blocks, 256 thr). Block 0 zeroes acc.
__global__ __launch_bounds__(256) void k_scan(const float* __restrict__ pts,
                                              const float* __restrict__ gt,
                                              const float* __restrict__ up,
                                              const float* __restrict__ off,
                                              unsigned long long* __restrict__ keys,
                                              unsigned* __restrict__ rowmin,
                                              unsigned* __restrict__ colmin,
                                              float* __restrict__ acc) {
  __shared__ float4 sc[512];   // 8 KB
  int blk = blockIdx.x;
  int tid = threadIdx.x;
  if (blk == 0 && tid < 16) acc[tid] = 0.f;

  if (blk < 512) {
    // ------- cham_row: up/off points vs gt candidates -------
    int qb = blk >> 3;           // [0,64)
    int seg = blk & 7;           // [0,8)
    int wb = qb >> 3;            // [0,8)
    int which = wb >> 2;         // 0=off, 1=up
    int b = wb & 3;
    int r0 = (qb & 7) * 1024 + tid * 4;   // [0,8192)
    {
      const float* gtb = gt + (size_t)b * NGG * 6 + (size_t)seg * 512 * 6;
      int i0 = tid * 2;
      const float4* g4 = (const float4*)(gtb + (size_t)i0 * 6);
      float4 u0 = g4[0], u1 = g4[1], u2 = g4[2];
      sc[i0] = make_float4(u0.x, u0.y, u0.z,
                           fmaf(u0.x, u0.x, fmaf(u0.y, u0.y, u0.z * u0.z)));
      sc[i0 + 1] = make_float4(u1.z, u1.w, u2.x,
                               fmaf(u1.z, u1.z, fmaf(u1.w, u1.w, u2.x * u2.x)));
    }
    const float* src = which ? up : off;
    const float4* s4 = (const float4*)src;
    size_t fb = ((size_t)(b * NUU + r0) * 3) >> 2;
    float4 A = s4[fb], B = s4[fb + 1], C = s4[fb + 2];
    float q0x = A.x, q0y = A.y, q0z = A.z;
    float q1x = A.w, q1y = B.x, q1z = B.y;
    float q2x = B.z, q2y = B.w, q2z = C.x;
    float q3x = C.y, q3y = C.z, q3z = C.w;
    float qq0 = fmaf(q0x, q0x, fmaf(q0y, q0y, q0z * q0z));
    float qq1 = fmaf(q1x, q1x, fmaf(q1y, q1y, q1z * q1z));
    float qq2 = fmaf(q2x, q2x, fmaf(q2y, q2y, q2z * q2z));
    float qq3 = fmaf(q3x, q3x, fmaf(q3y, q3y, q3z * q3z));
    float a0x = -2.f * q0x, a0y = -2.f * q0y, a0z = -2.f * q0z;
    float a1x = -2.f * q1x, a1y = -2.f * q1y, a1z = -2.f * q1z;
    float a2x = -2.f * q2x, a2y = -2.f * q2y, a2z = -2.f * q2z;
    float a3x = -2.f * q3x, a3y = -2.f * q3y, a3z = -2.f * q3z;
    __syncthreads();
    float b0 = 3.4e38f, b1 = 3.4e38f, b2 = 3.4e38f, b3 = 3.4e38f;
#pragma unroll 4
    for (int j = 0; j < 512; ++j) {
      float4 c = sc[j];
      float t;
      t = fmaf(c.x, a0x, c.w); t = fmaf(c.y, a0y, t); t = fmaf(c.z, a0z, t); b0 = fminf(b0, t);
      t = fmaf(c.x, a1x, c.w); t = fmaf(c.y, a1y, t); t = fmaf(c.z, a1z, t); b1 = fminf(b1, t);
      t = fmaf(c.x, a2x, c.w); t = fmaf(c.y, a2y, t); t = fmaf(c.z, a2z, t); b2 = fminf(b2, t);
      t = fmaf(c.x, a3x, c.w); t = fmaf(c.y, a3y, t); t = fmaf(c.z, a3z, t); b3 = fminf(b3, t);
    }
    int gr = which * 32768 + b * NUU + r0;
    atomicMin(&rowmin[gr + 0], fkey32(b0 + qq0));
    atomicMin(&rowmin[gr + 1], fkey32(b1 + qq1));
    atomicMin(&rowmin[gr + 2], fkey32(b2 + qq2));
    atomicMin(&rowmin[gr + 3], fkey32(b3 + qq3));

  } else if (blk < 1024) {
    // ------- cham_col: gt points vs up/off candidates -------
    int blk2 = blk - 512;
    int qb = blk2 >> 4;          // [0,32)
    int seg = blk2 & 15;         // [0,16)
    int which = qb >> 4;         // 0=off, 1=up
    int b = (qb >> 2) & 3;
    int m0 = (qb & 3) * 1024 + tid * 4;   // [0,4096)
    const float* src = which ? up : off;
    if (tid < 128) {
      const float* sb = src + (size_t)b * NUU * 3 + (size_t)seg * 512 * 3;
      int i0 = tid * 4;
      const float4* s4 = (const float4*)(sb + (size_t)i0 * 3);
      float4 u0 = s4[0], u1 = s4[1], u2 = s4[2];
      sc[i0] = make_float4(u0.x, u0.y, u0.z,
                           fmaf(u0.x, u0.x, fmaf(u0.y, u0.y, u0.z * u0.z)));
      sc[i0 + 1] = make_float4(u0.w, u1.x, u1.y,
                               fmaf(u0.w, u0.w, fmaf(u1.x, u1.x, u1.y * u1.y)));
      sc[i0 + 2] = make_float4(u1.z, u1.w, u2.x,
                               fmaf(u1.z, u1.z, fmaf(u1.w, u1.w, u2.x * u2.x)));
      sc[i0 + 3] = make_float4(u2.y, u2.z, u2.w,
                               fmaf(u2.y, u2.y, fmaf(u2.z, u2.z, u2.w * u2.w)));
    }
    const float* g = gt + (size_t)b * NGG * 6 + (size_t)m0 * 6;
    float q0x = g[0],  q0y = g[1],  q0z = g[2];
    float q1x = g[6],  q1y = g[7],  q1z = g[8];
    float q2x = g[12], q2y = g[13], q2z = g[14];
    float q3x = g[18], q3y = g[19], q3z = g[20];
    float qq0 = fmaf(q0x, q0x, fmaf(q0y, q0y, q0z * q0z));
    float qq1 = fmaf(q1x, q1x, fmaf(q1y, q1y, q1z * q1z));
    float qq2 = fmaf(q2x, q2x, fmaf(q2y, q2y, q2z * q2z));
    float qq3 = fmaf(q3x, q3x, fmaf(q3y, q3y, q3z * q3z));
    float a0x = -2.f * q0x, a0y = -2.f * q0y, a0z = -2.f * q0z;
    float a1x = -2.f * q1x, a1y = -2.f * q1y, a1z = -2.f * q1z;
    float a2x = -2.f * q2x, a2y = -2.f * q2y, a2z = -2.f * q2z;
    float a3x = -2.f * q3x, a3y = -2.f * q3y, a3z = -2.f * q3z;
    __syncthreads();
    float b0 = 3.4e38f, b1 = 3.4e38f, b2 = 3.4e38f, b3 = 3.4e38f;
#pragma unroll 4
    for (int j = 0; j < 512; ++j) {
      float4 c = sc[j];
      float t;
      t = fmaf(c.x, a0x, c.w); t = fmaf(c.y, a0y, t); t = fmaf(c.z, a0z, t); b0 = fminf(b0, t);
      t = fmaf(c.x, a1x, c.w); t = fmaf(c.y, a1y, t); t = fmaf(c.z, a1z, t); b1 = fminf(b1, t);
      t = fmaf(c.x, a2x, c.w); t = fmaf(c.y, a2y, t); t = fmaf(c.z, a2z, t); b2 = fminf(b2, t);
      t = fmaf(c.x, a3x, c.w); t = fmaf(c.y, a3y, t); t = fmaf(c.z, a3z, t); b3 = fminf(b3, t);
    }
    int gc = which * 16384 + b * NGG + m0;
    atomicMin(&colmin[gc + 0], fkey32(b0 + qq0));
    atomicMin(&colmin[gc + 1], fkey32(b1 + qq1));
    atomicMin(&colmin[gc + 2], fkey32(b2 + qq2));
    atomicMin(&colmin[gc + 3], fkey32(b3 + qq3));

  } else {
    // ------- argmin: pts vs gt candidates (keyed: dist<<32 | idx) -------
    int blk3 = blk - 1024;
    int qb = blk3 >> 4;          // [0,16)
    int seg = blk3 & 15;         // [0,16), 256 candidates each
    int b = qb >> 2;
    int m0 = (qb & 3) * 1024 + tid * 4;   // [0,4096)
    if (tid < 128) {
      const float* gtb = gt + (size_t)b * NGG * 6 + (size_t)seg * 256 * 6;
      int i0 = tid * 2;
      const float4* g4 = (const float4*)(gtb + (size_t)i0 * 6);
      float4 u0 = g4[0], u1 = g4[1], u2 = g4[2];
      sc[i0] = make_float4(u0.x, u0.y, u0.z,
                           fmaf(u0.x, u0.x, fmaf(u0.y, u0.y, u0.z * u0.z)));
      sc[i0 + 1] = make_float4(u1.z, u1.w, u2.x,
                               fmaf(u1.z, u1.z, fmaf(u1.w, u1.w, u2.x * u2.x)));
    }
    size_t fb = ((size_t)(b * NN + m0) * 3) >> 2;
    const float4* p4 = (const float4*)pts;
    float4 A = p4[fb], B = p4[fb + 1], C = p4[fb + 2];
    float q0x = A.x, q0y = A.y, q0z = A.z;
    float q1x = A.w, q1y = B.x, q1z = B.y;
    float q2x = B.z, q2y = B.w, q2z = C.x;
    float q3x = C.y, q3y = C.z, q3z = C.w;
    float a0x = -2.f * q0x, a0y = -2.f * q0y, a0z = -2.f * q0z;
    float a1x = -2.f * q1x, a1y = -2.f * q1y, a1z = -2.f * q1z;
    float a2x = -2.f * q2x, a2y = -2.f * q2y, a2z = -2.f * q2z;
    float a3x = -2.f * q3x, a3y = -2.f * q3y, a3z = -2.f * q3z;
    __syncthreads();
    float b0 = 3.4e38f, b1 = 3.4e38f, b2 = 3.4e38f, b3 = 3.4e38f;
    int i0 = 0, i1 = 0, i2 = 0, i3 = 0;
#pragma unroll 4
    for (int j = 0; j < 256; ++j) {
      float4 c = sc[j];
      float t; bool cc;
      t = fmaf(c.x, a0x, c.w); t = fmaf(c.y, a0y, t); t = fmaf(c.z, a0z, t);
      cc = t < b0; b0 = cc ? t : b0; i0 = cc ? j : i0;
      t = fmaf(c.x, a1x, c.w); t = fmaf(c.y, a1y, t); t = fmaf(c.z, a1z, t);
      cc = t < b1; b1 = cc ? t : b1; i1 = cc ? j : i1;
      t = fmaf(c.x, a2x, c.w); t = fmaf(c.y, a2y, t); t = fmaf(c.z, a2z, t);
      cc = t < b2; b2 = cc ? t : b2; i2 = cc ? j : i2;
      t = fmaf(c.x, a3x, c.w); t = fmaf(c.y, a3y, t); t = fmaf(c.z, a3z, t);
      cc = t < b3; b3 = cc ? t : b3; i3 = cc ? j : i3;
    }
    int q = b * NN + m0;
    int base = seg * 256;
    atomicMin(&keys[q + 0], ((unsigned long long)fkey32(b0) << 32) | (unsigned)(base + i0));
    atomicMin(&keys[q + 1], ((unsigned long long)fkey32(b1) << 32) | (unsigned)(base + i1));
    atomicMin(&keys[q + 2], ((unsigned long long)fkey32(b2) << 32) | (unsigned)(base + i2));
    atomicMin(&keys[q + 3], ((unsigned long long)fkey32(b3) << 32) | (unsigned)(base + i3));
  }
}

// ------------- fused: postgather (blocks 0..63) + reduce mins (64..447) -
__global__ __launch_bounds__(256) void k_post(
    const float* __restrict__ ori_pre, const float* __restrict__ nor_pre,
    const float* __restrict__ gt, const unsigned long long* __restrict__ keys,
    const unsigned* __restrict__ rowmin, const unsigned* __restrict__ colmin,
    float* __restrict__ nor_gt, float* __restrict__ ori_pro, float* __restrict__ acc) {
  __shared__ float sb1[4], sb2[4];
  int blk = blockIdx.x;
  if (blk < 64) {
    int q = blk * 256 + threadIdx.x;
    int b = q >> 12;
    float ox = ori_pre[q * 3 + 0], oy = ori_pre[q * 3 + 1], oz = ori_pre[q * 3 + 2];
    float n1 = sqrtf(fmaf(ox, ox, fmaf(oy, oy, oz * oz)) + 1e-8f) + 1e-10f;
    ox /= n1; oy /= n1; oz /= n1;
    float px = nor_pre[q * 3 + 0], py = nor_pre[q * 3 + 1], pz = nor_pre[q * 3 + 2];
    float n2 = sqrtf(fmaf(px, px, fmaf(py, py, pz * pz)) + 1e-8f) + 1e-10f;
    px /= n2; py /= n2; pz /= n2;
    unsigned idx = (unsigned)(keys[q] & 0xffffffffULL);
    const float* g = gt + (size_t)b * NGG * 6 + (size_t)idx * 6 + 3;
    float gx = g[0], gy = g[1], gz = g[2];
    float dn = fmaf(gx, ox, fmaf(gy, oy, gz * oz));
    float vx = ox - gx * dn, vy = oy - gy * dn, vz = oz - gz * dn;
    float n3 = sqrtf(fmaf(vx, vx, fmaf(vy, vy, vz * vz)) + 1e-8f) + 1e-10f;
    vx /= n3; vy /= n3; vz /= n3;
    nor_gt[q * 3 + 0] = gx; nor_gt[q * 3 + 1] = gy; nor_gt[q * 3 + 2] = gz;
    ori_pro[q * 3 + 0] = vx; ori_pro[q * 3 + 1] = vy; ori_pro[q * 3 + 2] = vz;
    float na = fmaxf(sqrtf(fmaf(gx, gx, fmaf(gy, gy, gz * gz))), 1e-8f);
    float nb = fmaxf(sqrtf(fmaf(px, px, fmaf(py, py, pz * pz))), 1e-8f);
    float cs = fmaf(gx, px, fmaf(gy, py, gz * pz)) / (na * nb);
    float t_nor = 1.f - fabsf(cs);
    float t_ori = fabsf(dn);
    float s1 = block_sum_256(t_nor, sb1);
    float s2 = block_sum_256(t_ori, sb2);
    if (threadIdx.x == 0) {
      atomicAdd(&acc[1], s1);
      atomicAdd(&acc[2], s2);
    }
  } else {
    int rblk = blk - 64;   // [0,384)
    float v;
    int slot;
    if (rblk < 256) {
      int i = rblk * 256 + threadIdx.x;
      v = unfkey32(rowmin[i]);
      slot = (i >> 15) ? 5 : 3;   // 0=offset rows -> acc3, 1=up rows -> acc5
    } else {
      int i = (rblk - 256) * 256 + threadIdx.x;
      v = unfkey32(colmin[i]);
      slot = (i >> 14) ? 6 : 4;   // 0=offset cols -> acc4, 1=up cols -> acc6
    }
    float s = block_sum_256(v, sb1);
    if (threadIdx.x == 0) atomicAdd(&acc[slot], s);
  }
}

// sorted insertion of (D, CI) into the 6-register chain (exact)
#define INSERT6(D, CI)                                                          \
  {                                                                             \
    float d_ = (D); int ci_ = (CI);                                             \
    bool cc; float nd; int ni;                                                  \
    cc = d_ < d0; nd = cc ? d_ : d0; d_ = cc ? d0 : d_; ni = cc ? ci_ : i0; ci_ = cc ? i0 : ci_; d0 = nd; i0 = ni; \
    cc = d_ < d1; nd = cc ? d_ : d1; d_ = cc ? d1 : d_; ni = cc ? ci_ : i1; ci_ = cc ? i1 : ci_; d1 = nd; i1 = ni; \
    cc = d_ < d2; nd = cc ? d_ : d2; d_ = cc ? d2 : d_; ni = cc ? ci_ : i2; ci_ = cc ? i2 : ci_; d2 = nd; i2 = ni; \
    cc = d_ < d3; nd = cc ? d_ : d3; d_ = cc ? d3 : d_; ni = cc ? ci_ : i3; ci_ = cc ? i3 : ci_; d3 = nd; i3 = ni; \
    cc = d_ < d4; nd = cc ? d_ : d4; d_ = cc ? d4 : d_; ni = cc ? ci_ : i4; ci_ = cc ? i4 : ci_; d4 = nd; i4 = ni; \
    cc = d_ < d5; nd = cc ? d_ : d5;                    ni = cc ? ci_ : i5;                      d5 = nd; i5 = ni; \
  }

// ------------- KNN (K=6) + fused loss_smooth + last-block finalize -----
// R8 structure; inner loop 4-wide unrolled: one gate compare + one branch
// per 4 candidates (12 FMA + 3-min tree). Each insert individually gated
// on its own d <= T (T >= true 6th-best => pruning stays exact; extra
// inserts harmless). __launch_bounds__(512,8) pins VGPR <= 64 so the
// unroll cannot cost occupancy.
__global__ __launch_bounds__(512, 8) void k_knn_smooth(const float* __restrict__ pts,
                                                       const float* __restrict__ nor_gt,
                                                       const float* __restrict__ ori_pro,
                                                       float* __restrict__ acc,
                                                       float* __restrict__ out) {
  __shared__ float4 sp[1152];    // 1024 + 128 pad = 18 KB
  __shared__ float sbuf[8];
  int tid = threadIdx.x;
  int q_local = tid >> 5;        // [0,16)
  int t = tid & 31;
  int q = blockIdx.x * 16 + q_local;
  int b = q >> 12;
  int n = q & 4095;
  const float* pb = pts + (size_t)b * NN * 3;
  float qx = pb[n * 3 + 0], qy = pb[n * 3 + 1], qz = pb[n * 3 + 2];
  float qx2 = -2.f * qx, qy2 = -2.f * qy, qz2 = -2.f * qz;
  float d0 = 3.4e38f, d1 = 3.4e38f, d2 = 3.4e38f,
        d3 = 3.4e38f, d4 = 3.4e38f, d5 = 3.4e38f;
  int i0 = 0, i1 = 0, i2 = 0, i3 = 0, i4 = 0, i5 = 0;
  int toff = t + (t >> 3);       // loop-invariant part of the swizzle

  for (int ch = 0; ch < 4; ++ch) {
    if (tid < 256) {
      const float4* p4 = (const float4*)(pb + (size_t)(ch * 1024 + tid * 4) * 3);
      float4 u0 = p4[0], u1 = p4[1], u2 = p4[2];
      int il = tid * 4;
      int si = il + (il >> 3);   // pad-swizzle: kills 64B-stride conflicts
      sp[si] = make_float4(u0.x, u0.y, u0.z,
                           fmaf(u0.x, u0.x, fmaf(u0.y, u0.y, u0.z * u0.z)));
      sp[si + 1] = make_float4(u0.w, u1.x, u1.y,
                               fmaf(u0.w, u0.w, fmaf(u1.x, u1.x, u1.y * u1.y)));
      sp[si + 2] = make_float4(u1.z, u1.w, u2.x,
                               fmaf(u1.z, u1.z, fmaf(u1.w, u1.w, u2.x * u2.x)));
      sp[si + 3] = make_float4(u2.y, u2.z, u2.w,
                               fmaf(u2.y, u2.y, fmaf(u2.z, u2.z, u2.w * u2.w)));
    }
    __syncthreads();
    int cbase = ch << 10;
    for (int jo = 0; jo < 4; ++jo) {
      // refresh shared threshold (stale-high is safe: only extra inserts)
      float T = d5;
#pragma unroll
      for (int o = 16; o > 0; o >>= 1) T = fminf(T, __shfl_xor(T, o, 32));
#pragma unroll
      for (int ji = 0; ji < 2; ++ji) {
        int c0 = (((jo << 1) | ji) << 7) | t;     // 4 cands: c0,+32,+64,+96
        int s0 = c0 + (c0 >> 3);                  // c0 mult of 128 in high part
        // swizzled offsets: (c0+32k) + ((c0+32k)>>3) = s0 + 36k
        float4 p0 = sp[s0];
        float4 p1 = sp[s0 + 36];
        float4 p2 = sp[s0 + 72];
        float4 p3 = sp[s0 + 108];
        float da = fmaf(p0.x, qx2, p0.w); da = fmaf(p0.y, qy2, da); da = fmaf(p0.z, qz2, da);
        float db = fmaf(p1.x, qx2, p1.w); db = fmaf(p1.y, qy2, db); db = fmaf(p1.z, qz2, db);
        float dc = fmaf(p2.x, qx2, p2.w); dc = fmaf(p2.y, qy2, dc); dc = fmaf(p2.z, qz2, dc);
        float dd = fmaf(p3.x, qx2, p3.w); dd = fmaf(p3.y, qy2, dd); dd = fmaf(p3.z, qz2, dd);
        float mmin = fminf(fminf(da, db), fminf(dc, dd));
        if (mmin <= T) {
          int cg = cbase | c0;
          if (da <= T) INSERT6(da, cg)
          if (db <= T) INSERT6(db, cg + 32)
          if (dc <= T) INSERT6(dc, cg + 64)
          if (dd <= T) INSERT6(dd, cg + 96)
        }
      }
    }
    __syncthreads();
  }
  (void)toff;

  // 6-round tournament over the 32 per-lane sorted lists (keys unique:
  // idx disambiguates; a lane pops at most 6 times so heads stay real).
  int myid = 0;
#pragma unroll
  for (int r = 0; r < 6; ++r) {
    unsigned long long h = ((unsigned long long)fkey32(d0) << 32) | (unsigned)i0;
    unsigned long long m = h;
#pragma unroll
    for (int o = 16; o > 0; o >>= 1) {
      unsigned long long other = __shfl_xor(m, o, 32);
      m = (other < m) ? other : m;
    }
    if (t == r) myid = (int)(m & 0xffffffffULL);
    if (h == m) {   // this lane won round r: pop head
      d0 = d1; i0 = i1; d1 = d2; i1 = i2; d2 = d3; i2 = i3;
      d3 = d4; i3 = i4; d4 = d5; i4 = i5; d5 = 3.4e38f;
    }
  }

  float sum = 0.f;
  if (t < 6) {
    const float* gq = nor_gt + (size_t)q * 3;
    float ngx = gq[0], ngy = gq[1], ngz = gq[2];
    const float* oq = ori_pro + (size_t)q * 3;
    float box = oq[0], boy = oq[1], boz = oq[2];
    float rx = boy * ngz - boz * ngy;
    float ry = boz * ngx - box * ngz;
    float rz = box * ngy - boy * ngx;
    float nbo = fmaxf(sqrtf(fmaf(box, box, fmaf(boy, boy, boz * boz))), 1e-8f);
    float nrot = fmaxf(sqrtf(fmaf(rx, rx, fmaf(ry, ry, rz * rz))), 1e-8f);
    const float* gn = nor_gt + (size_t)(b * 4096 + myid) * 3;
    const float* go = ori_pro + (size_t)(b * 4096 + myid) * 3;
    float gnx = gn[0], gny = gn[1], gnz = gn[2];
    float gox = go[0], goy = go[1], goz = go[2];
    float ndv = fmaf(gnx, ngx, fmaf(gny, ngy, gnz * ngz));
    float wv = (expf(-ndv / 0.3f) * 10.f + 1.f) < 4.f ? 1.f : 5.f;
    float ngo = fmaxf(sqrtf(fmaf(gox, gox, fmaf(goy, goy, goz * goz))), 1e-8f);
    float c0 = fmaf(gox, box, fmaf(goy, boy, goz * boz)) / (ngo * nbo);
    float c1 = fmaf(gox, rx, fmaf(goy, ry, goz * rz)) / (ngo * nrot);
    float cosv = fminf(1.f - fabsf(c0), 1.f - fabsf(c1));
    sum = wv * cosv;
  }
  float s = block_sum_512(sum, sbuf);

  // ---- finalize: tid 0 only (fence count = gridDim, not threads) ----
  if (tid == 0) {
    atomicAdd(&acc[0], s);
    __threadfence();
    unsigned c = atomicAdd((unsigned*)(acc + 9), 1u);
    if (c == gridDim.x - 1) {
      __threadfence();
      float a0 = atomicAdd(&acc[0], 0.f);
      float a1 = atomicAdd(&acc[1], 0.f);
      float a2 = atomicAdd(&acc[2], 0.f);
      float a3 = atomicAdd(&acc[3], 0.f);
      float a4 = atomicAdd(&acc[4], 0.f);
      float a5 = atomicAdd(&acc[5], 0.f);
      float a6 = atomicAdd(&acc[6], 0.f);
      float loss_smooth = a0 / 98304.f;            // B*N*K
      float loss_nor = a1 / 16384.f;               // B*N
      float loss_nor_ori = a2 / 16384.f;
      float lco = a3 / 32768.f + a4 / 16384.f;     // B*NU rows + B*NG cols
      float lc = a5 / 32768.f + a6 / 16384.f;
      float loss_cd = lc + 0.4f * lco;
      float loss = loss_smooth + loss_nor + 0.1f * loss_nor_ori + 200.f * loss_cd;
      out[0] = loss;
      out[1] = loss_smooth;
      out[2] = loss_nor;
      out[3] = lco;
      out[4] = loss_nor_ori;
      out[5] = lc;
      out[6] = lc;
    }
  }
}

extern "C" void kernel_launch(void* const* d_in, const int* in_sizes, int n_in,
                              void* d_out, int out_size, void* d_ws, size_t ws_size,
                              hipStream_t stream) {
  (void)in_sizes; (void)n_in; (void)out_size; (void)ws_size;
  const float* ori_pre = (const float*)d_in[0];
  const float* nor_pre = (const float*)d_in[1];
  const float* xyz_up = (const float*)d_in[2];
  const float* xyz_off = (const float*)d_in[3];
  const float* pts = (const float*)d_in[4];
  const float* gt = (const float*)d_in[5];
  float* out = (float*)d_out;
  char* ws = (char*)d_ws;

  float* acc = (float*)(ws + 0);                                   // 16 floats: 0..6 sums, 9 done ctr
  unsigned long long* keys = (unsigned long long*)(ws + 512);      // 16384 u64 = 128 KB
  unsigned* rowmin = (unsigned*)(ws + 512 + 131072);               // 65536 u32 = 256 KB
  unsigned* colmin = (unsigned*)(ws + 512 + 131072 + 262144);      // 32768 u32 = 128 KB
  float* nor_gt = (float*)(ws + 512 + 131072 + 262144 + 131072);   // 49152 f32 = 192 KB
  float* ori_pro = (float*)(ws + 512 + 131072 + 262144 + 131072 + 196608);

  hipMemsetAsync(ws + 512, 0xFF, 131072 + 262144 + 131072, stream);

  k_scan<<<1280, 256, 0, stream>>>(pts, gt, xyz_up, xyz_off, keys, rowmin,
                                   colmin, acc);
  k_post<<<448, 256, 0, stream>>>(ori_pre, nor_pre, gt, keys, rowmin, colmin,
                                  nor_gt, ori_pro, acc);
  k_knn_smooth<<<1024, 512, 0, stream>>>(pts, nor_gt, ori_pro, acc, out);
}

// Round 10
// 185.492 us; speedup vs baseline: 1.5995x; 1.0464x over previous
//
#include <hip/hip_runtime.h>
#include <stdint.h>

#define NN 4096
#define NGG 4096
#define NUU 8192

// monotone float->uint mapping (order-preserving incl. negatives)
__device__ __forceinline__ unsigned fkey32(float f) {
  unsigned u = __float_as_uint(f);
  return u ^ (((int)u >> 31) | 0x80000000u);
}
__device__ __forceinline__ float unfkey32(unsigned k) {
  unsigned m = (k & 0x80000000u) ? 0x80000000u : 0xFFFFFFFFu;
  return __uint_as_float(k ^ m);
}

// ---------------- block-wide sum (blockDim.x == 256) -------------------
__device__ __forceinline__ float block_sum_256(float v, float* sbuf) {
#pragma unroll
  for (int o = 32; o > 0; o >>= 1) v += __shfl_down(v, o, 64);
  int lane = threadIdx.x & 63;
  int w = threadIdx.x >> 6;
  if (lane == 0) sbuf[w] = v;
  __syncthreads();
  float r = 0.f;
  if (threadIdx.x == 0) r = sbuf[0] + sbuf[1] + sbuf[2] + sbuf[3];
  __syncthreads();
  return r;
}

// ---------------- block-wide sum (blockDim.x == 512) -------------------
__device__ __forceinline__ float block_sum_512(float v, float* sbuf) {
#pragma unroll
  for (int o = 32; o > 0; o >>= 1) v += __shfl_down(v, o, 64);
  int lane = threadIdx.x & 63;
  int w = threadIdx.x >> 6;
  if (lane == 0) sbuf[w] = v;
  __syncthreads();
  float r = 0.f;
  if (threadIdx.x == 0) {
#pragma unroll
    for (int i = 0; i < 8; ++i) r += sbuf[i];
  }
  __syncthreads();
  return r;
}

// ---------------- fused scan: argmin + chamfer rows + chamfer cols -----
// R2-proven layout (Q=4, 1280 blocks, 256 thr). Block 0 zeroes acc.
__global__ __launch_bounds__(256) void k_scan(const float* __restrict__ pts,
                                              const float* __restrict__ gt,
                                              const float* __restrict__ up,
                                              const float* __restrict__ off,
                                              unsigned long long* __restrict__ keys,
                                              unsigned* __restrict__ rowmin,
                                              unsigned* __restrict__ colmin,
                                              float* __restrict__ acc) {
  __shared__ float4 sc[512];   // 8 KB
  int blk = blockIdx.x;
  int tid = threadIdx.x;
  if (blk == 0 && tid < 16) acc[tid] = 0.f;

  if (blk < 512) {
    // ------- cham_row: up/off points vs gt candidates -------
    int qb = blk >> 3;           // [0,64)
    int seg = blk & 7;           // [0,8)
    int wb = qb >> 3;            // [0,8)
    int which = wb >> 2;         // 0=off, 1=up
    int b = wb & 3;
    int r0 = (qb & 7) * 1024 + tid * 4;   // [0,8192)
    {
      const float* gtb = gt + (size_t)b * NGG * 6 + (size_t)seg * 512 * 6;
      int i0 = tid * 2;
      const float4* g4 = (const float4*)(gtb + (size_t)i0 * 6);
      float4 u0 = g4[0], u1 = g4[1], u2 = g4[2];
      sc[i0] = make_float4(u0.x, u0.y, u0.z,
                           fmaf(u0.x, u0.x, fmaf(u0.y, u0.y, u0.z * u0.z)));
      sc[i0 + 1] = make_float4(u1.z, u1.w, u2.x,
                               fmaf(u1.z, u1.z, fmaf(u1.w, u1.w, u2.x * u2.x)));
    }
    const float* src = which ? up : off;
    const float4* s4 = (const float4*)src;
    size_t fb = ((size_t)(b * NUU + r0) * 3) >> 2;
    float4 A = s4[fb], B = s4[fb + 1], C = s4[fb + 2];
    float q0x = A.x, q0y = A.y, q0z = A.z;
    float q1x = A.w, q1y = B.x, q1z = B.y;
    float q2x = B.z, q2y = B.w, q2z = C.x;
    float q3x = C.y, q3y = C.z, q3z = C.w;
    float qq0 = fmaf(q0x, q0x, fmaf(q0y, q0y, q0z * q0z));
    float qq1 = fmaf(q1x, q1x, fmaf(q1y, q1y, q1z * q1z));
    float qq2 = fmaf(q2x, q2x, fmaf(q2y, q2y, q2z * q2z));
    float qq3 = fmaf(q3x, q3x, fmaf(q3y, q3y, q3z * q3z));
    float a0x = -2.f * q0x, a0y = -2.f * q0y, a0z = -2.f * q0z;
    float a1x = -2.f * q1x, a1y = -2.f * q1y, a1z = -2.f * q1z;
    float a2x = -2.f * q2x, a2y = -2.f * q2y, a2z = -2.f * q2z;
    float a3x = -2.f * q3x, a3y = -2.f * q3y, a3z = -2.f * q3z;
    __syncthreads();
    float b0 = 3.4e38f, b1 = 3.4e38f, b2 = 3.4e38f, b3 = 3.4e38f;
#pragma unroll 4
    for (int j = 0; j < 512; ++j) {
      float4 c = sc[j];
      float t;
      t = fmaf(c.x, a0x, c.w); t = fmaf(c.y, a0y, t); t = fmaf(c.z, a0z, t); b0 = fminf(b0, t);
      t = fmaf(c.x, a1x, c.w); t = fmaf(c.y, a1y, t); t = fmaf(c.z, a1z, t); b1 = fminf(b1, t);
      t = fmaf(c.x, a2x, c.w); t = fmaf(c.y, a2y, t); t = fmaf(c.z, a2z, t); b2 = fminf(b2, t);
      t = fmaf(c.x, a3x, c.w); t = fmaf(c.y, a3y, t); t = fmaf(c.z, a3z, t); b3 = fminf(b3, t);
    }
    int gr = which * 32768 + b * NUU + r0;
    atomicMin(&rowmin[gr + 0], fkey32(b0 + qq0));
    atomicMin(&rowmin[gr + 1], fkey32(b1 + qq1));
    atomicMin(&rowmin[gr + 2], fkey32(b2 + qq2));
    atomicMin(&rowmin[gr + 3], fkey32(b3 + qq3));

  } else if (blk < 1024) {
    // ------- cham_col: gt points vs up/off candidates -------
    int blk2 = blk - 512;
    int qb = blk2 >> 4;          // [0,32)
    int seg = blk2 & 15;         // [0,16)
    int which = qb >> 4;         // 0=off, 1=up
    int b = (qb >> 2) & 3;
    int m0 = (qb & 3) * 1024 + tid * 4;   // [0,4096)
    const float* src = which ? up : off;
    if (tid < 128) {
      const float* sb = src + (size_t)b * NUU * 3 + (size_t)seg * 512 * 3;
      int i0 = tid * 4;
      const float4* s4 = (const float4*)(sb + (size_t)i0 * 3);
      float4 u0 = s4[0], u1 = s4[1], u2 = s4[2];
      sc[i0] = make_float4(u0.x, u0.y, u0.z,
                           fmaf(u0.x, u0.x, fmaf(u0.y, u0.y, u0.z * u0.z)));
      sc[i0 + 1] = make_float4(u0.w, u1.x, u1.y,
                               fmaf(u0.w, u0.w, fmaf(u1.x, u1.x, u1.y * u1.y)));
      sc[i0 + 2] = make_float4(u1.z, u1.w, u2.x,
                               fmaf(u1.z, u1.z, fmaf(u1.w, u1.w, u2.x * u2.x)));
      sc[i0 + 3] = make_float4(u2.y, u2.z, u2.w,
                               fmaf(u2.y, u2.y, fmaf(u2.z, u2.z, u2.w * u2.w)));
    }
    const float* g = gt + (size_t)b * NGG * 6 + (size_t)m0 * 6;
    float q0x = g[0],  q0y = g[1],  q0z = g[2];
    float q1x = g[6],  q1y = g[7],  q1z = g[8];
    float q2x = g[12], q2y = g[13], q2z = g[14];
    float q3x = g[18], q3y = g[19], q3z = g[20];
    float qq0 = fmaf(q0x, q0x, fmaf(q0y, q0y, q0z * q0z));
    float qq1 = fmaf(q1x, q1x, fmaf(q1y, q1y, q1z * q1z));
    float qq2 = fmaf(q2x, q2x, fmaf(q2y, q2y, q2z * q2z));
    float qq3 = fmaf(q3x, q3x, fmaf(q3y, q3y, q3z * q3z));
    float a0x = -2.f * q0x, a0y = -2.f * q0y, a0z = -2.f * q0z;
    float a1x = -2.f * q1x, a1y = -2.f * q1y, a1z = -2.f * q1z;
    float a2x = -2.f * q2x, a2y = -2.f * q2y, a2z = -2.f * q2z;
    float a3x = -2.f * q3x, a3y = -2.f * q3y, a3z = -2.f * q3z;
    __syncthreads();
    float b0 = 3.4e38f, b1 = 3.4e38f, b2 = 3.4e38f, b3 = 3.4e38f;
#pragma unroll 4
    for (int j = 0; j < 512; ++j) {
      float4 c = sc[j];
      float t;
      t = fmaf(c.x, a0x, c.w); t = fmaf(c.y, a0y, t); t = fmaf(c.z, a0z, t); b0 = fminf(b0, t);
      t = fmaf(c.x, a1x, c.w); t = fmaf(c.y, a1y, t); t = fmaf(c.z, a1z, t); b1 = fminf(b1, t);
      t = fmaf(c.x, a2x, c.w); t = fmaf(c.y, a2y, t); t = fmaf(c.z, a2z, t); b2 = fminf(b2, t);
      t = fmaf(c.x, a3x, c.w); t = fmaf(c.y, a3y, t); t = fmaf(c.z, a3z, t); b3 = fminf(b3, t);
    }
    int gc = which * 16384 + b * NGG + m0;
    atomicMin(&colmin[gc + 0], fkey32(b0 + qq0));
    atomicMin(&colmin[gc + 1], fkey32(b1 + qq1));
    atomicMin(&colmin[gc + 2], fkey32(b2 + qq2));
    atomicMin(&colmin[gc + 3], fkey32(b3 + qq3));

  } else {
    // ------- argmin: pts vs gt candidates (keyed: dist<<32 | idx) -------
    int blk3 = blk - 1024;
    int qb = blk3 >> 4;          // [0,16)
    int seg = blk3 & 15;         // [0,16), 256 candidates each
    int b = qb >> 2;
    int m0 = (qb & 3) * 1024 + tid * 4;   // [0,4096)
    if (tid < 128) {
      const float* gtb = gt + (size_t)b * NGG * 6 + (size_t)seg * 256 * 6;
      int i0 = tid * 2;
      const float4* g4 = (const float4*)(gtb + (size_t)i0 * 6);
      float4 u0 = g4[0], u1 = g4[1], u2 = g4[2];
      sc[i0] = make_float4(u0.x, u0.y, u0.z,
                           fmaf(u0.x, u0.x, fmaf(u0.y, u0.y, u0.z * u0.z)));
      sc[i0 + 1] = make_float4(u1.z, u1.w, u2.x,
                               fmaf(u1.z, u1.z, fmaf(u1.w, u1.w, u2.x * u2.x)));
    }
    size_t fb = ((size_t)(b * NN + m0) * 3) >> 2;
    const float4* p4 = (const float4*)pts;
    float4 A = p4[fb], B = p4[fb + 1], C = p4[fb + 2];
    float q0x = A.x, q0y = A.y, q0z = A.z;
    float q1x = A.w, q1y = B.x, q1z = B.y;
    float q2x = B.z, q2y = B.w, q2z = C.x;
    float q3x = C.y, q3y = C.z, q3z = C.w;
    float a0x = -2.f * q0x, a0y = -2.f * q0y, a0z = -2.f * q0z;
    float a1x = -2.f * q1x, a1y = -2.f * q1y, a1z = -2.f * q1z;
    float a2x = -2.f * q2x, a2y = -2.f * q2y, a2z = -2.f * q2z;
    float a3x = -2.f * q3x, a3y = -2.f * q3y, a3z = -2.f * q3z;
    __syncthreads();
    float b0 = 3.4e38f, b1 = 3.4e38f, b2 = 3.4e38f, b3 = 3.4e38f;
    int i0 = 0, i1 = 0, i2 = 0, i3 = 0;
#pragma unroll 4
    for (int j = 0; j < 256; ++j) {
      float4 c = sc[j];
      float t; bool cc;
      t = fmaf(c.x, a0x, c.w); t = fmaf(c.y, a0y, t); t = fmaf(c.z, a0z, t);
      cc = t < b0; b0 = cc ? t : b0; i0 = cc ? j : i0;
      t = fmaf(c.x, a1x, c.w); t = fmaf(c.y, a1y, t); t = fmaf(c.z, a1z, t);
      cc = t < b1; b1 = cc ? t : b1; i1 = cc ? j : i1;
      t = fmaf(c.x, a2x, c.w); t = fmaf(c.y, a2y, t); t = fmaf(c.z, a2z, t);
      cc = t < b2; b2 = cc ? t : b2; i2 = cc ? j : i2;
      t = fmaf(c.x, a3x, c.w); t = fmaf(c.y, a3y, t); t = fmaf(c.z, a3z, t);
      cc = t < b3; b3 = cc ? t : b3; i3 = cc ? j : i3;
    }
    int q = b * NN + m0;
    int base = seg * 256;
    atomicMin(&keys[q + 0], ((unsigned long long)fkey32(b0) << 32) | (unsigned)(base + i0));
    atomicMin(&keys[q + 1], ((unsigned long long)fkey32(b1) << 32) | (unsigned)(base + i1));
    atomicMin(&keys[q + 2], ((unsigned long long)fkey32(b2) << 32) | (unsigned)(base + i2));
    atomicMin(&keys[q + 3], ((unsigned long long)fkey32(b3) << 32) | (unsigned)(base + i3));
  }
}

// ------------- fused: postgather (blocks 0..63) + reduce mins (64..447) -
__global__ __launch_bounds__(256) void k_post(
    const float* __restrict__ ori_pre, const float* __restrict__ nor_pre,
    const float* __restrict__ gt, const unsigned long long* __restrict__ keys,
    const unsigned* __restrict__ rowmin, const unsigned* __restrict__ colmin,
    float* __restrict__ nor_gt, float* __restrict__ ori_pro, float* __restrict__ acc) {
  __shared__ float sb1[4], sb2[4];
  int blk = blockIdx.x;
  if (blk < 64) {
    int q = blk * 256 + threadIdx.x;
    int b = q >> 12;
    float ox = ori_pre[q * 3 + 0], oy = ori_pre[q * 3 + 1], oz = ori_pre[q * 3 + 2];
    float n1 = sqrtf(fmaf(ox, ox, fmaf(oy, oy, oz * oz)) + 1e-8f) + 1e-10f;
    ox /= n1; oy /= n1; oz /= n1;
    float px = nor_pre[q * 3 + 0], py = nor_pre[q * 3 + 1], pz = nor_pre[q * 3 + 2];
    float n2 = sqrtf(fmaf(px, px, fmaf(py, py, pz * pz)) + 1e-8f) + 1e-10f;
    px /= n2; py /= n2; pz /= n2;
    unsigned idx = (unsigned)(keys[q] & 0xffffffffULL);
    const float* g = gt + (size_t)b * NGG * 6 + (size_t)idx * 6 + 3;
    float gx = g[0], gy = g[1], gz = g[2];
    float dn = fmaf(gx, ox, fmaf(gy, oy, gz * oz));
    float vx = ox - gx * dn, vy = oy - gy * dn, vz = oz - gz * dn;
    float n3 = sqrtf(fmaf(vx, vx, fmaf(vy, vy, vz * vz)) + 1e-8f) + 1e-10f;
    vx /= n3; vy /= n3; vz /= n3;
    nor_gt[q * 3 + 0] = gx; nor_gt[q * 3 + 1] = gy; nor_gt[q * 3 + 2] = gz;
    ori_pro[q * 3 + 0] = vx; ori_pro[q * 3 + 1] = vy; ori_pro[q * 3 + 2] = vz;
    float na = fmaxf(sqrtf(fmaf(gx, gx, fmaf(gy, gy, gz * gz))), 1e-8f);
    float nb = fmaxf(sqrtf(fmaf(px, px, fmaf(py, py, pz * pz))), 1e-8f);
    float cs = fmaf(gx, px, fmaf(gy, py, gz * pz)) / (na * nb);
    float t_nor = 1.f - fabsf(cs);
    float t_ori = fabsf(dn);
    float s1 = block_sum_256(t_nor, sb1);
    float s2 = block_sum_256(t_ori, sb2);
    if (threadIdx.x == 0) {
      atomicAdd(&acc[1], s1);
      atomicAdd(&acc[2], s2);
    }
  } else {
    int rblk = blk - 64;   // [0,384)
    float v;
    int slot;
    if (rblk < 256) {
      int i = rblk * 256 + threadIdx.x;
      v = unfkey32(rowmin[i]);
      slot = (i >> 15) ? 5 : 3;   // 0=offset rows -> acc3, 1=up rows -> acc5
    } else {
      int i = (rblk - 256) * 256 + threadIdx.x;
      v = unfkey32(colmin[i]);
      slot = (i >> 14) ? 6 : 4;   // 0=offset cols -> acc4, 1=up cols -> acc6
    }
    float s = block_sum_256(v, sb1);
    if (threadIdx.x == 0) atomicAdd(&acc[slot], s);
  }
}

// sorted insertion of (D, CI) into the 6-register chain (exact)
#define INSERT6(D, CI)                                                          \
  {                                                                             \
    float d_ = (D); int ci_ = (CI);                                             \
    bool cc; float nd; int ni;                                                  \
    cc = d_ < d0; nd = cc ? d_ : d0; d_ = cc ? d0 : d_; ni = cc ? ci_ : i0; ci_ = cc ? i0 : ci_; d0 = nd; i0 = ni; \
    cc = d_ < d1; nd = cc ? d_ : d1; d_ = cc ? d1 : d_; ni = cc ? ci_ : i1; ci_ = cc ? i1 : ci_; d1 = nd; i1 = ni; \
    cc = d_ < d2; nd = cc ? d_ : d2; d_ = cc ? d2 : d_; ni = cc ? ci_ : i2; ci_ = cc ? i2 : ci_; d2 = nd; i2 = ni; \
    cc = d_ < d3; nd = cc ? d_ : d3; d_ = cc ? d3 : d_; ni = cc ? ci_ : i3; ci_ = cc ? i3 : ci_; d3 = nd; i3 = ni; \
    cc = d_ < d4; nd = cc ? d_ : d4; d_ = cc ? d4 : d_; ni = cc ? ci_ : i4; ci_ = cc ? i4 : ci_; d4 = nd; i4 = ni; \
    cc = d_ < d5; nd = cc ? d_ : d5;                    ni = cc ? ci_ : i5;                      d5 = nd; i5 = ni; \
  }

// ------------- KNN (K=6) + fused loss_smooth + last-block finalize -----
// Two-pass exact selection. All 4096 candidates live in 74 KB padded LDS
// (2 blocks/CU = 16 waves/CU, ~= the measured occupancy of the previous
// version). Pass A: per-lane min over its 128 candidates (no inserts).
// tau = 6-round wave-min-with-removal over the 32 lane minima: the removed
// lanes hold >=6 DISTINCT candidates (disjoint lane candidate sets) with
// values <= tau, so true 6th-best <= tau -- pruning on d <= tau is exact.
// Pass B: rescan (bitwise-identical FMAs), insert only survivors (~10-20
// per query), so the 48-inst INSERT6 chain is wave-rare.
__global__ __launch_bounds__(512, 4) void k_knn_smooth(const float* __restrict__ pts,
                                                       const float* __restrict__ nor_gt,
                                                       const float* __restrict__ ori_pro,
                                                       float* __restrict__ acc,
                                                       float* __restrict__ out) {
  __shared__ float4 sp[4608];    // 4096 + 512 pad = 72 KB
  __shared__ float sbuf[8];
  int tid = threadIdx.x;
  int q_local = tid >> 5;        // [0,16)
  int t = tid & 31;
  int q = blockIdx.x * 16 + q_local;
  int b = q >> 12;
  int n = q & 4095;
  const float* pb = pts + (size_t)b * NN * 3;

  // ---- stage all 4096 points (8 per thread), pad-swizzled ----
  {
    int il = tid * 8;
    const float4* p4 = (const float4*)(pb + (size_t)il * 3);
    float4 u0 = p4[0], u1 = p4[1], u2 = p4[2], u3 = p4[3], u4 = p4[4], u5 = p4[5];
    int si = il + (il >> 3);     // il mult of 8 -> 8 stores contiguous
    sp[si + 0] = make_float4(u0.x, u0.y, u0.z,
                             fmaf(u0.x, u0.x, fmaf(u0.y, u0.y, u0.z * u0.z)));
    sp[si + 1] = make_float4(u0.w, u1.x, u1.y,
                             fmaf(u0.w, u0.w, fmaf(u1.x, u1.x, u1.y * u1.y)));
    sp[si + 2] = make_float4(u1.z, u1.w, u2.x,
                             fmaf(u1.z, u1.z, fmaf(u1.w, u1.w, u2.x * u2.x)));
    sp[si + 3] = make_float4(u2.y, u2.z, u2.w,
                             fmaf(u2.y, u2.y, fmaf(u2.z, u2.z, u2.w * u2.w)));
    sp[si + 4] = make_float4(u3.x, u3.y, u3.z,
                             fmaf(u3.x, u3.x, fmaf(u3.y, u3.y, u3.z * u3.z)));
    sp[si + 5] = make_float4(u3.w, u4.x, u4.y,
                             fmaf(u3.w, u3.w, fmaf(u4.x, u4.x, u4.y * u4.y)));
    sp[si + 6] = make_float4(u4.z, u4.w, u5.x,
                             fmaf(u4.z, u4.z, fmaf(u4.w, u4.w, u5.x * u5.x)));
    sp[si + 7] = make_float4(u5.y, u5.z, u5.w,
                             fmaf(u5.y, u5.y, fmaf(u5.z, u5.z, u5.w * u5.w)));
  }
  __syncthreads();

  float qx = pb[n * 3 + 0], qy = pb[n * 3 + 1], qz = pb[n * 3 + 2];
  float qx2 = -2.f * qx, qy2 = -2.f * qy, qz2 = -2.f * qz;

  // ---- pass A: per-lane min over its 128 candidates ----
  float m = 3.4e38f;
#pragma unroll 4
  for (int gg = 0; gg < 32; ++gg) {
    int c0 = (gg << 7) | t;          // cands c0, +32, +64, +96
    int s0 = c0 + (c0 >> 3);         // swizzle: +32k -> +36k
    float4 p0 = sp[s0];
    float4 p1 = sp[s0 + 36];
    float4 p2 = sp[s0 + 72];
    float4 p3 = sp[s0 + 108];
    float da = fmaf(p0.x, qx2, p0.w); da = fmaf(p0.y, qy2, da); da = fmaf(p0.z, qz2, da);
    float db = fmaf(p1.x, qx2, p1.w); db = fmaf(p1.y, qy2, db); db = fmaf(p1.z, qz2, db);
    float dc = fmaf(p2.x, qx2, p2.w); dc = fmaf(p2.y, qy2, dc); dc = fmaf(p2.z, qz2, dc);
    float dd = fmaf(p3.x, qx2, p3.w); dd = fmaf(p3.y, qy2, dd); dd = fmaf(p3.z, qz2, dd);
    m = fminf(m, fminf(fminf(da, db), fminf(dc, dd)));
  }

  // ---- tau: 6th distinct value among the 32 lane minima (upper bound
  //      on the true 6th-best; dup-collapse only loosens it -> safe) ----
  float mv = m, tau = 3.4e38f;
#pragma unroll
  for (int r = 0; r < 6; ++r) {
    float w = mv;
#pragma unroll
    for (int o = 16; o > 0; o >>= 1) w = fminf(w, __shfl_xor(w, o, 32));
    tau = w;
    if (mv == w) mv = 3.4e38f;       // remove winner(s)
  }

  // ---- pass B: rescan, insert survivors only ----
  float d0 = 3.4e38f, d1 = 3.4e38f, d2 = 3.4e38f,
        d3 = 3.4e38f, d4 = 3.4e38f, d5 = 3.4e38f;
  int i0 = 0, i1 = 0, i2 = 0, i3 = 0, i4 = 0, i5 = 0;
#pragma unroll 2
  for (int gg = 0; gg < 32; ++gg) {
    int c0 = (gg << 7) | t;
    int s0 = c0 + (c0 >> 3);
    float4 p0 = sp[s0];
    float4 p1 = sp[s0 + 36];
    float4 p2 = sp[s0 + 72];
    float4 p3 = sp[s0 + 108];
    float da = fmaf(p0.x, qx2, p0.w); da = fmaf(p0.y, qy2, da); da = fmaf(p0.z, qz2, da);
    float db = fmaf(p1.x, qx2, p1.w); db = fmaf(p1.y, qy2, db); db = fmaf(p1.z, qz2, db);
    float dc = fmaf(p2.x, qx2, p2.w); dc = fmaf(p2.y, qy2, dc); dc = fmaf(p2.z, qz2, dc);
    float dd = fmaf(p3.x, qx2, p3.w); dd = fmaf(p3.y, qy2, dd); dd = fmaf(p3.z, qz2, dd);
    float mmin = fminf(fminf(da, db), fminf(dc, dd));
    if (mmin <= tau) {
      if (da <= tau) INSERT6(da, c0)
      if (db <= tau) INSERT6(db, c0 + 32)
      if (dc <= tau) INSERT6(dc, c0 + 64)
      if (dd <= tau) INSERT6(dd, c0 + 96)
    }
  }

  // 6-round tournament over the 32 per-lane sorted lists (keys unique:
  // idx disambiguates; >=6 real survivors exist wave-wide, and real keys
  // always beat the +inf fillers).
  int myid = 0;
#pragma unroll
  for (int r = 0; r < 6; ++r) {
    unsigned long long h = ((unsigned long long)fkey32(d0) << 32) | (unsigned)i0;
    unsigned long long mk = h;
#pragma unroll
    for (int o = 16; o > 0; o >>= 1) {
      unsigned long long other = __shfl_xor(mk, o, 32);
      mk = (other < mk) ? other : mk;
    }
    if (t == r) myid = (int)(mk & 0xffffffffULL);
    if (h == mk) {   // this lane won round r: pop head
      d0 = d1; i0 = i1; d1 = d2; i1 = i2; d2 = d3; i2 = i3;
      d3 = d4; i3 = i4; d4 = d5; i4 = i5; d5 = 3.4e38f;
    }
  }

  float sum = 0.f;
  if (t < 6) {
    const float* gq = nor_gt + (size_t)q * 3;
    float ngx = gq[0], ngy = gq[1], ngz = gq[2];
    const float* oq = ori_pro + (size_t)q * 3;
    float box = oq[0], boy = oq[1], boz = oq[2];
    float rx = boy * ngz - boz * ngy;
    float ry = boz * ngx - box * ngz;
    float rz = box * ngy - boy * ngx;
    float nbo = fmaxf(sqrtf(fmaf(box, box, fmaf(boy, boy, boz * boz))), 1e-8f);
    float nrot = fmaxf(sqrtf(fmaf(rx, rx, fmaf(ry, ry, rz * rz))), 1e-8f);
    const float* gn = nor_gt + (size_t)(b * 4096 + myid) * 3;
    const float* go = ori_pro + (size_t)(b * 4096 + myid) * 3;
    float gnx = gn[0], gny = gn[1], gnz = gn[2];
    float gox = go[0], goy = go[1], goz = go[2];
    float ndv = fmaf(gnx, ngx, fmaf(gny, ngy, gnz * ngz));
    float wv = (expf(-ndv / 0.3f) * 10.f + 1.f) < 4.f ? 1.f : 5.f;
    float ngo = fmaxf(sqrtf(fmaf(gox, gox, fmaf(goy, goy, goz * goz))), 1e-8f);
    float c0 = fmaf(gox, box, fmaf(goy, boy, goz * boz)) / (ngo * nbo);
    float c1 = fmaf(gox, rx, fmaf(goy, ry, goz * rz)) / (ngo * nrot);
    float cosv = fminf(1.f - fabsf(c0), 1.f - fabsf(c1));
    sum = wv * cosv;
  }
  float s = block_sum_512(sum, sbuf);

  // ---- finalize: tid 0 only (fence count = gridDim, not threads) ----
  if (tid == 0) {
    atomicAdd(&acc[0], s);
    __threadfence();
    unsigned c = atomicAdd((unsigned*)(acc + 9), 1u);
    if (c == gridDim.x - 1) {
      __threadfence();
      float a0 = atomicAdd(&acc[0], 0.f);
      float a1 = atomicAdd(&acc[1], 0.f);
      float a2 = atomicAdd(&acc[2], 0.f);
      float a3 = atomicAdd(&acc[3], 0.f);
      float a4 = atomicAdd(&acc[4], 0.f);
      float a5 = atomicAdd(&acc[5], 0.f);
      float a6 = atomicAdd(&acc[6], 0.f);
      float loss_smooth = a0 / 98304.f;            // B*N*K
      float loss_nor = a1 / 16384.f;               // B*N
      float loss_nor_ori = a2 / 16384.f;
      float lco = a3 / 32768.f + a4 / 16384.f;     // B*NU rows + B*NG cols
      float lc = a5 / 32768.f + a6 / 16384.f;
      float loss_cd = lc + 0.4f * lco;
      float loss = loss_smooth + loss_nor + 0.1f * loss_nor_ori + 200.f * loss_cd;
      out[0] = loss;
      out[1] = loss_smooth;
      out[2] = loss_nor;
      out[3] = lco;
      out[4] = loss_nor_ori;
      out[5] = lc;
      out[6] = lc;
    }
  }
}

extern "C" void kernel_launch(void* const* d_in, const int* in_sizes, int n_in,
                              void* d_out, int out_size, void* d_ws, size_t ws_size,
                              hipStream_t stream) {
  (void)in_sizes; (void)n_in; (void)out_size; (void)ws_size;
  const float* ori_pre = (const float*)d_in[0];
  const float* nor_pre = (const float*)d_in[1];
  const float* xyz_up = (const float*)d_in[2];
  const float* xyz_off = (const float*)d_in[3];
  const float* pts = (const float*)d_in[4];
  const float* gt = (const float*)d_in[5];
  float* out = (float*)d_out;
  char* ws = (char*)d_ws;

  float* acc = (float*)(ws + 0);                                   // 16 floats: 0..6 sums, 9 done ctr
  unsigned long long* keys = (unsigned long long*)(ws + 512);      // 16384 u64 = 128 KB
  unsigned* rowmin = (unsigned*)(ws + 512 + 131072);               // 65536 u32 = 256 KB
  unsigned* colmin = (unsigned*)(ws + 512 + 131072 + 262144);      // 32768 u32 = 128 KB
  float* nor_gt = (float*)(ws + 512 + 131072 + 262144 + 131072);   // 49152 f32 = 192 KB
  float* ori_pro = (float*)(ws + 512 + 131072 + 262144 + 131072 + 196608);

  hipMemsetAsync(ws + 512, 0xFF, 131072 + 262144 + 131072, stream);

  k_scan<<<1280, 256, 0, stream>>>(pts, gt, xyz_up, xyz_off, keys, rowmin,
                                   colmin, acc);
  k_post<<<448, 256, 0, stream>>>(ori_pre, nor_pre, gt, keys, rowmin, colmin,
                                  nor_gt, ori_pro, acc);
  k_knn_smooth<<<1024, 512, 0, stream>>>(pts, nor_gt, ori_pro, acc, out);
}